// Round 13
// baseline (1032.293 us; speedup 1.0000x reference)
//
#include <hip/hip_runtime.h>
#include <math.h>

#define NPTS   20001
#define NREAL  20000
#define EPAD   1200000
#define KK     64
#define RADF   0.1125f

typedef _Float16 half8_t __attribute__((ext_vector_type(8)));
typedef float    floatx4 __attribute__((ext_vector_type(4)));

__device__ __forceinline__ float sgnf(float v){ return v>0.f ? 1.f : (v<0.f ? -1.f : 0.f); }
__device__ __forceinline__ _Float16 lo16(unsigned u){ return __builtin_bit_cast(_Float16, (unsigned short)(u & 0xffffu)); }
__device__ __forceinline__ _Float16 hi16(unsigned u){ return __builtin_bit_cast(_Float16, (unsigned short)(u >> 16)); }
// deterministic fp32 -> packed f16 hi/lo split (hi in low 16 bits). Same split the GEMM
// used to do in-kernel -> producer-side packing is BIT-IDENTICAL math, just hoisted.
__device__ __forceinline__ unsigned packf(float v){
  _Float16 h = (_Float16)v;
  _Float16 l = (_Float16)(v - (float)h);
  return (unsigned)__builtin_bit_cast(unsigned short, h)
       | ((unsigned)__builtin_bit_cast(unsigned short, l) << 16);
}

// byte-offset XOR swizzle for [rows][32]-half (64B-row) LDS tiles (kept from r12; the
// r11 "8-bank" audit was WRONG — both layouts are conflict-free — but the swizzled
// [64*32] form is smaller (no pad) and measured neutral-to-positive).
__device__ __forceinline__ void* swzp(void* base, int byteoff){
  return (void*)((char*)base + (byteoff ^ (((byteoff >> 6) & 7) << 4)));
}
__device__ __forceinline__ const void* swzp(const void* base, int byteoff){
  return (const void*)((const char*)base + (byteoff ^ (((byteoff >> 6) & 7) << 4)));
}

// ---------------- CSR build (edge_src is sorted; pad edges have dst==NREAL) ----------------
__global__ void k_find_ereal(const int* __restrict__ dst, int* __restrict__ ereal){
  int lo=0, hi=EPAD;
  while(lo<hi){ int mid=(lo+hi)>>1; if(dst[mid]==NREAL) hi=mid; else lo=mid+1; }
  *ereal = lo;
}

__global__ void k_csr(const int* __restrict__ src, const int* __restrict__ erealp,
                      int* __restrict__ row_start){
  int i = blockIdx.x*blockDim.x + threadIdx.x;
  if(i > NPTS) return;
  int E = *erealp;
  int lo=0, hi=E;
  while(lo<hi){ int mid=(lo+hi)>>1; if(src[mid] < i) lo=mid+1; else hi=mid; }
  row_start[i] = lo;
}

__global__ void k_build_f(const float* __restrict__ feats, float* __restrict__ f){
  int idx = blockIdx.x*blockDim.x + threadIdx.x;
  if(idx >= NPTS*13) return;
  int i = idx/13, c = idx - i*13;
  f[idx] = (c==0) ? 1.f : feats[i*12 + (c-1)];
}

// ---- feature pre-pass: relu + split + pack, once per layer.
__global__ void k_cvtF(const float* __restrict__ x, unsigned* __restrict__ Fp, int total){
  int idx = blockIdx.x*blockDim.x + threadIdx.x;
  if(idx >= total) return;
  Fp[idx] = packf(fmaxf(x[idx], 0.f));
}

// ---------------- per-edge geometry (exact port of ball_to_cube + window) ----------------
__device__ __forceinline__ void edge_geom(float ox, float oy, float oz,
                                          float& win, float& t0, float& t1, float& t2, int& f0p){
  const float eps = 1e-9f;
  float sq = ox*ox + oy*oy + oz*oz;
  float u = 1.f - sq;
  win = fminf(fmaxf(u*u*u, 0.f), 1.f);
  float norm = sqrtf(sq + eps);
  float rxy2 = ox*ox + oy*oy;
  bool polar = (1.25f*oz*oz > rxy2);
  float s_p = sqrtf(3.f*norm/(norm + fabsf(oz) + eps));
  float s_n = norm / sqrtf(rxy2 + eps);
  float s = polar ? s_p : s_n;
  float xc = ox*s, yc = oy*s;
  float zc = polar ? sgnf(oz)*norm : 1.5f*oz;
  if(sq < 1e-12f){ xc = 0.f; yc = 0.f; zc = 0.f; }
  float r = sqrtf(xc*xc + yc*yc + eps);
  bool c1 = fabsf(xc) >= fabsf(yc);
  float xs = (fabsf(xc) < eps) ? eps : xc;
  float ys = (fabsf(yc) < eps) ? eps : yc;
  const float fop = 1.2732395447351628f; // float32(4/pi)
  float a = c1 ? sgnf(xc)*r : sgnf(yc)*r*fop*atanf(xc/ys);
  float b = c1 ? sgnf(xc)*r*fop*atanf(yc/xs) : sgnf(yc)*r;
  if(xc*xc + yc*yc < 1e-12f){ a = 0.f; b = 0.f; }
  float g0 = fminf(fmaxf((a *0.5f+0.5f)*3.f, 0.f), 3.f);
  float g1 = fminf(fmaxf((b *0.5f+0.5f)*3.f, 0.f), 3.f);
  float g2 = fminf(fmaxf((zc*0.5f+0.5f)*3.f, 0.f), 3.f);
  float f00 = floorf(g0), f01 = floorf(g1), f02 = floorf(g2);
  t0 = g0 - f00; t1 = g1 - f01; t2 = g2 - f02;
  f0p = (int)f00 | ((int)f01 << 2) | ((int)f02 << 4);
}

// ---- k_geom: per-edge staged data, computed ONCE (shared by all 4 scatter layers).
__global__ __launch_bounds__(256) void k_geom(const float* __restrict__ pos,
    const int* __restrict__ esrc, const int* __restrict__ edst,
    float4* __restrict__ gw, int4* __restrict__ gmz)
{
  int e = blockIdx.x*blockDim.x + threadIdx.x;
  if(e >= EPAD) return;
  const int sn = esrc[e], d = edst[e];
  const float ox = (pos[d*3+0]-pos[sn*3+0])/RADF;
  const float oy = (pos[d*3+1]-pos[sn*3+1])/RADF;
  const float oz = (pos[d*3+2]-pos[sn*3+2])/RADF;
  float win, t0, t1, t2; int f0p;
  edge_geom(ox, oy, oz, win, t0, t1, t2, f0p);
  const int i0 = f0p & 3, i1 = (f0p>>2) & 3, i2 = f0p >> 4;
  const int X0 = i0 << 4, X1 = ((i0+1)&3) << 4;
  const int Y0 = i1 << 2, Y1 = ((i1+1)&3) << 2;
  const int Z0 = i2, Z1 = (i2+1) & 3;
  const float wx0 = win*(1.f-t0), wx1 = win*t0;
  const float wy0 = 1.f-t1, wy1 = t1;
  const float wz0 = 1.f-t2, wz1 = t2;
  gw[e] = make_float4(wx0*wy0, wx0*wy1, wx1*wy0, wx1*wy1);
  const int p0 = Z0 & 1;
  const float zA = p0 ? wz1 : wz0;                  // weight for parity-0 (even z) cell
  const int   cA = p0 ? Z1 : Z0;                    // even-z cell
  const int   cB = p0 ? Z0 : Z1;                    // odd-z cell
  const int cells0 = (X0|Y0|cA) | ((X0|Y1|cA)<<8) | ((X1|Y0|cA)<<16) | ((X1|Y1|cA)<<24);
  const int cells1 = (X0|Y0|cB) | ((X0|Y1|cB)<<8) | ((X1|Y0|cB)<<16) | ((X1|Y1|cB)<<24);
  gmz[e] = make_int4(__float_as_int(zA), cells0, cells1, d);
}

// ------- MFMA scatter CIN=64 (r12 structure, measured 127us). v6 delta: OUT3=0 epilogue
// emits PACKED pre-split B (u32 hi|lo) so the GEMM skips fp32 load + per-kstep splitting.
// Split is deterministic -> GEMM results bit-identical.
template<int OUT3>
__global__ __launch_bounds__(256) void k_scat64m(
    const unsigned* __restrict__ Fp, const float4* __restrict__ gw,
    const int4* __restrict__ gmz, const int* __restrict__ row_start,
    unsigned* __restrict__ B, int node_base,
    const float* __restrict__ W3, float* __restrict__ out)
{
  __shared__ __align__(128) _Float16 Wh[64*32];
  __shared__ __align__(128) _Float16 Wl[64*32];
  __shared__ __align__(128) _Float16 Fh[64*32];
  __shared__ __align__(128) _Float16 Fl[64*32];
  __shared__ __align__(16) float4 Sq[32];
  __shared__ __align__(16) int4   Smd[32];
  __shared__ float red[16];

  const int tid  = threadIdx.x;
  const int node = node_base + blockIdx.x;
  const int wv   = tid >> 6;
  const int lane = tid & 63;
  const int frow = lane & 15;
  const int fb   = (lane >> 4) << 4;   // frag col byte offset

  floatx4 acc[4];
  #pragma unroll
  for(int nt=0;nt<4;++nt){ acc[nt][0]=0.f; acc[nt][1]=0.f; acc[nt][2]=0.f; acc[nt][3]=0.f; }

  half8_t hz;
  #pragma unroll
  for(int q8=0;q8<8;++q8) hz[q8] = (_Float16)0;

  const int e0 = row_start[node], e1 = row_start[node+1];

  for(int eb = e0; eb < e1; eb += 32){
    const int n = (e1 - eb < 32) ? (e1 - eb) : 32;
    __syncthreads();
    if(wv == 0){
      if(lane < 32){
        int ei = eb + lane; if(ei >= e1) ei = e1 - 1;
        Sq[lane]  = gw[ei];
        Smd[lane] = gmz[ei];
      }
    } else {
      for(int j = tid - 64; j < 512; j += 192){
        if(j < 256) ((half8_t*)Wh)[j]       = hz;
        else        ((half8_t*)Wl)[j - 256] = hz;
      }
    }
    __syncthreads();
    {
      half8_t hreg, lreg;
      #pragma unroll
      for(int j=0;j<8;++j){
        const int dst = Smd[wv*8 + j].w;
        const unsigned u = Fp[(size_t)dst*64 + lane];
        hreg[j] = lo16(u);
        lreg[j] = hi16(u);
      }
      *(half8_t*)swzp(Fh, (lane<<6) + (wv<<4)) = hreg;
      *(half8_t*)swzp(Fl, (lane<<6) + (wv<<4)) = lreg;
    }
    if(lane < 8){
      const int ei = wv*8 + lane;
      if(ei < n){
        const float4 q  = Sq[ei];
        const int4   md = Smd[ei];
        const float zA = __int_as_float(md.x), zB = 1.f - zA;
        #pragma unroll
        for(int t=0;t<8;++t){
          const int   cells = (t < 4) ? md.y : md.z;
          const float zz    = (t < 4) ? zA : zB;
          const int   cell  = (cells >> ((t & 3) * 8)) & 255;
          const float qq    = ((t&3)==0) ? q.x : ((t&3)==1) ? q.y : ((t&3)==2) ? q.z : q.w;
          const float wgt   = qq * zz;
          const _Float16 h  = (_Float16)wgt;
          *(_Float16*)swzp(Wh, (cell<<6) + (ei<<1)) = h;
          *(_Float16*)swzp(Wl, (cell<<6) + (ei<<1)) = (_Float16)(wgt - (float)h);
        }
      }
    }
    __syncthreads();
    const half8_t ah = *(const half8_t*)swzp(Wh, ((wv*16 + frow)<<6) + fb);
    const half8_t al = *(const half8_t*)swzp(Wl, ((wv*16 + frow)<<6) + fb);
    #pragma unroll
    for(int nt=0; nt<4; ++nt){
      const half8_t bh = *(const half8_t*)swzp(Fh, ((nt*16 + frow)<<6) + fb);
      const half8_t bl = *(const half8_t*)swzp(Fl, ((nt*16 + frow)<<6) + fb);
      acc[nt] = __builtin_amdgcn_mfma_f32_16x16x32_f16(ah, bh, acc[nt], 0, 0, 0);
      acc[nt] = __builtin_amdgcn_mfma_f32_16x16x32_f16(al, bh, acc[nt], 0, 0, 0);
      acc[nt] = __builtin_amdgcn_mfma_f32_16x16x32_f16(ah, bl, acc[nt], 0, 0, 0);
    }
  }

  if(!OUT3){
    unsigned* Bg = B + (size_t)blockIdx.x*4096;
    #pragma unroll
    for(int nt=0;nt<4;++nt)
      #pragma unroll
      for(int r=0;r<4;++r){
        const int cell = wv*16 + (lane>>4)*4 + r;
        Bg[cell*64 + nt*16 + (lane&15)] = packf(acc[nt][r]);
      }
  } else {
    float s0=0.f, s1=0.f, s2=0.f;
    #pragma unroll
    for(int nt=0;nt<4;++nt){
      #pragma unroll
      for(int r=0;r<4;++r){
        const int cell = wv*16 + (lane>>4)*4 + r;
        const int j3   = (cell*64 + nt*16 + (lane&15)) * 3;
        const float v  = acc[nt][r];
        s0 = fmaf(v, W3[j3+0], s0);
        s1 = fmaf(v, W3[j3+1], s1);
        s2 = fmaf(v, W3[j3+2], s2);
      }
    }
    #pragma unroll
    for(int off = 32; off > 0; off >>= 1){
      s0 += __shfl_down(s0, off);
      s1 += __shfl_down(s1, off);
      s2 += __shfl_down(s2, off);
    }
    if(lane == 0){
      red[wv*4+0] = s0; red[wv*4+1] = s1; red[wv*4+2] = s2;
    }
    __syncthreads();
    if(tid == 0 && node < NREAL){
      out[node*3+0] += (red[0]+red[4]+red[8] +red[12])*(1.f/128.f);
      out[node*3+1] += (red[1]+red[5]+red[9] +red[13])*(1.f/128.f);
      out[node*3+2] += (red[2]+red[6]+red[10]+red[14])*(1.f/128.f);
    }
  }
}

// ------- MFMA scatter CIN=96 (r12 structure), packed-B epilogue.
__global__ __launch_bounds__(256) void k_scat96m(
    const unsigned* __restrict__ Fp, const float4* __restrict__ gw,
    const int4* __restrict__ gmz, const int* __restrict__ row_start,
    unsigned* __restrict__ B, int node_base)
{
  __shared__ __align__(128) _Float16 Wh[64*32];
  __shared__ __align__(128) _Float16 Wl[64*32];
  __shared__ __align__(128) _Float16 Fh[96*32];
  __shared__ __align__(128) _Float16 Fl[96*32];
  __shared__ __align__(16) float4 Sq[32];
  __shared__ __align__(16) int4   Smd[32];

  const int tid  = threadIdx.x;
  const int node = node_base + blockIdx.x;
  const int wv   = tid >> 6;
  const int lane = tid & 63;
  const int frow = lane & 15;
  const int fb   = (lane >> 4) << 4;

  floatx4 acc[6];
  #pragma unroll
  for(int nt=0;nt<6;++nt){ acc[nt][0]=0.f; acc[nt][1]=0.f; acc[nt][2]=0.f; acc[nt][3]=0.f; }

  half8_t hz;
  #pragma unroll
  for(int q8=0;q8<8;++q8) hz[q8] = (_Float16)0;

  const int e0 = row_start[node], e1 = row_start[node+1];

  for(int eb = e0; eb < e1; eb += 32){
    const int n = (e1 - eb < 32) ? (e1 - eb) : 32;
    __syncthreads();
    if(wv == 0){
      if(lane < 32){
        int ei = eb + lane; if(ei >= e1) ei = e1 - 1;
        Sq[lane]  = gw[ei];
        Smd[lane] = gmz[ei];
      }
    } else {
      for(int j = tid - 64; j < 512; j += 192){
        if(j < 256) ((half8_t*)Wh)[j]       = hz;
        else        ((half8_t*)Wl)[j - 256] = hz;
      }
    }
    __syncthreads();
    {
      half8_t h0, l0, h1, l1;
      #pragma unroll
      for(int j=0;j<8;++j){
        const int dst = Smd[wv*8 + j].w;
        const unsigned u = Fp[(size_t)dst*96 + lane];
        h0[j] = lo16(u);
        l0[j] = hi16(u);
        if(lane < 32){
          const unsigned u2 = Fp[(size_t)dst*96 + 64 + lane];
          h1[j] = lo16(u2);
          l1[j] = hi16(u2);
        }
      }
      *(half8_t*)swzp(Fh, (lane<<6) + (wv<<4)) = h0;
      *(half8_t*)swzp(Fl, (lane<<6) + (wv<<4)) = l0;
      if(lane < 32){
        *(half8_t*)swzp(Fh, ((64+lane)<<6) + (wv<<4)) = h1;
        *(half8_t*)swzp(Fl, ((64+lane)<<6) + (wv<<4)) = l1;
      }
    }
    if(lane < 8){
      const int ei = wv*8 + lane;
      if(ei < n){
        const float4 q  = Sq[ei];
        const int4   md = Smd[ei];
        const float zA = __int_as_float(md.x), zB = 1.f - zA;
        #pragma unroll
        for(int t=0;t<8;++t){
          const int   cells = (t < 4) ? md.y : md.z;
          const float zz    = (t < 4) ? zA : zB;
          const int   cell  = (cells >> ((t & 3) * 8)) & 255;
          const float qq    = ((t&3)==0) ? q.x : ((t&3)==1) ? q.y : ((t&3)==2) ? q.z : q.w;
          const float wgt   = qq * zz;
          const _Float16 h  = (_Float16)wgt;
          *(_Float16*)swzp(Wh, (cell<<6) + (ei<<1)) = h;
          *(_Float16*)swzp(Wl, (cell<<6) + (ei<<1)) = (_Float16)(wgt - (float)h);
        }
      }
    }
    __syncthreads();
    const half8_t ah = *(const half8_t*)swzp(Wh, ((wv*16 + frow)<<6) + fb);
    const half8_t al = *(const half8_t*)swzp(Wl, ((wv*16 + frow)<<6) + fb);
    #pragma unroll
    for(int nt=0; nt<6; ++nt){
      const half8_t bh = *(const half8_t*)swzp(Fh, ((nt*16 + frow)<<6) + fb);
      const half8_t bl = *(const half8_t*)swzp(Fl, ((nt*16 + frow)<<6) + fb);
      acc[nt] = __builtin_amdgcn_mfma_f32_16x16x32_f16(ah, bh, acc[nt], 0, 0, 0);
      acc[nt] = __builtin_amdgcn_mfma_f32_16x16x32_f16(al, bh, acc[nt], 0, 0, 0);
      acc[nt] = __builtin_amdgcn_mfma_f32_16x16x32_f16(ah, bl, acc[nt], 0, 0, 0);
    }
  }

  unsigned* Bg = B + (size_t)blockIdx.x*6144;
  #pragma unroll
  for(int nt=0;nt<6;++nt)
    #pragma unroll
    for(int r=0;r<4;++r){
      const int cell = wv*16 + (lane>>4)*4 + r;
      Bg[cell*96 + nt*16 + (lane&15)] = packf(acc[nt][r]);
    }
}

// ------- scatter CIN=13 (RMW form), packed-B epilogue -------------------------------------
__global__ __launch_bounds__(128) void k_scat13(
    const float* __restrict__ feat, const float4* __restrict__ gw,
    const int4* __restrict__ gmz, const int* __restrict__ row_start,
    unsigned* __restrict__ B, int node_base)
{
  constexpr int CIN = 13, BSZ = KK*CIN, ESW = 4, CSTRIDE = BSZ + 8;
  __shared__ __align__(16) float Bl[ESW*CSTRIDE];
  const int tid  = threadIdx.x;
  const int node = node_base + blockIdx.x;

  for(int j = tid; j < ESW*CSTRIDE; j += 128) Bl[j] = 0.f;

  const int e0 = row_start[node], e1 = row_start[node+1];
  const int wv   = tid >> 6;
  const int lane = tid & 63;
  const int slot = lane >> 4;
  const int c    = lane & 15;
  const bool act = (c < CIN);
  float* Bp = Bl + slot*CSTRIDE;
  __syncthreads();

  if(act){
    for(int e = e0 + slot; e < e1; e += ESW){
      const float4 q  = gw[e];
      const int4   md = gmz[e];
      const float zA = __int_as_float(md.x);
      const float z  = wv ? (1.f - zA) : zA;
      const int   cp = wv ? md.z : md.y;
      float v = feat[(size_t)md.w*CIN + c] * z;
      const int b0 = ( cp        & 255)*CIN + c;
      const int b1 = ((cp >> 8)  & 255)*CIN + c;
      const int b2 = ((cp >> 16) & 255)*CIN + c;
      const int b3 = (((unsigned)cp) >> 24)*CIN + c;
      float o0 = Bp[b0], o1 = Bp[b1], o2 = Bp[b2], o3 = Bp[b3];
      o0 = fmaf(q.x, v, o0); o1 = fmaf(q.y, v, o1);
      o2 = fmaf(q.z, v, o2); o3 = fmaf(q.w, v, o3);
      Bp[b0] = o0; Bp[b1] = o1; Bp[b2] = o2; Bp[b3] = o3;
    }
  }
  __syncthreads();

  unsigned* Bg = B + (size_t)blockIdx.x*BSZ;
  for(int j = tid*4; j < BSZ; j += 512){
    float4 a = *(const float4*)&Bl[j];
    #pragma unroll
    for(int k = 1; k < ESW; ++k){
      const float4 t = *(const float4*)&Bl[k*CSTRIDE + j];
      a.x += t.x; a.y += t.y; a.z += t.z; a.w += t.w;
    }
    uint4 o;
    o.x = packf(a.x); o.y = packf(a.y); o.z = packf(a.z); o.w = packf(a.w);
    *(uint4*)&Bg[j] = o;
  }
}

// ---- W pre-pass: transpose + split fp32 -> f16 hi/lo.  WhT/WlT layout [64 cols][Kd k]
__global__ void k_cvtW(const float* __restrict__ W, _Float16* __restrict__ WhT,
                       _Float16* __restrict__ WlT, int Kd)
{
  int idx = blockIdx.x*blockDim.x + threadIdx.x;
  if(idx >= 64*Kd) return;
  int o = idx / Kd, k = idx - o*Kd;
  float w = W[(size_t)k*64 + o];
  _Float16 h = (_Float16)w;
  WhT[idx] = h;
  WlT[idx] = (_Float16)(w - (float)h);
}

// ---- MFMA GEMM v2: packed pre-split A (u32 hi|lo from the scatters), M-tile 128.
// Per wave per K32-step: 24 MFMA vs 12 frag b128 reads (r12 form was 12 vs 10) and
// zero split VALU. LDS 24KB (Ah/Al 8KB ea + Wh/Wl 4KB ea) -> 6 blocks/CU.
__global__ __launch_bounds__(256) void k_gemm_mfma(
    const unsigned* __restrict__ Ap, const _Float16* __restrict__ WhT,
    const _Float16* __restrict__ WlT, float* __restrict__ P,
    int M, int Kd, int node_base, int ksteps_per)
{
  __shared__ __align__(128) _Float16 Ah[128*32];
  __shared__ __align__(128) _Float16 Al[128*32];
  __shared__ __align__(128) _Float16 Bh[64*32];
  __shared__ __align__(128) _Float16 Blo[64*32];
  const int tid = threadIdx.x;
  const int mbase = blockIdx.x * 128;
  const int s = blockIdx.y;
  const int kt0 = s * ksteps_per * 32;
  const int kt1 = min(Kd, kt0 + ksteps_per*32);
  const int wv = tid >> 6, lane = tid & 63;
  const int arow = tid >> 1;            // A staging row 0..127
  const int aseg = (tid & 1) * 16;      // u32 seg within 32-wide tile
  const int wrow = tid >> 2;            // W staging row 0..63
  const int wseg = (tid & 3) * 8;       // half seg
  const int frow = lane & 15;
  const int fb   = (lane >> 4) << 4;

  floatx4 acc[2][4];
  #pragma unroll
  for(int rt=0;rt<2;++rt)
    #pragma unroll
    for(int c=0;c<4;++c){ acc[rt][c][0]=0.f; acc[rt][c][1]=0.f; acc[rt][c][2]=0.f; acc[rt][c][3]=0.f; }

  const int grow = mbase + arow;
  const unsigned* Arow = (grow < M) ? (Ap + (size_t)grow*Kd) : nullptr;
  const _Float16* WhRow = WhT + (size_t)wrow*Kd;
  const _Float16* WlRow = WlT + (size_t)wrow*Kd;

  for(int kt = kt0; kt < kt1; kt += 32){
    unsigned au[16];
    if(Arow){
      *(uint4*)&au[0]  = *(const uint4*)(Arow + kt + aseg);
      *(uint4*)&au[4]  = *(const uint4*)(Arow + kt + aseg + 4);
      *(uint4*)&au[8]  = *(const uint4*)(Arow + kt + aseg + 8);
      *(uint4*)&au[12] = *(const uint4*)(Arow + kt + aseg + 12);
    } else {
      #pragma unroll
      for(int j=0;j<16;++j) au[j] = 0u;
    }
    half8_t h0, h1, l0, l1;
    #pragma unroll
    for(int j=0;j<8;++j){
      h0[j] = lo16(au[j]);   l0[j] = hi16(au[j]);
      h1[j] = lo16(au[8+j]); l1[j] = hi16(au[8+j]);
    }
    half8_t wh = *(const half8_t*)(WhRow + kt + wseg);
    half8_t wl = *(const half8_t*)(WlRow + kt + wseg);
    __syncthreads();                        // previous iter's frag reads complete
    {
      const int ab = (arow<<6) + (aseg<<1);   // byte offset: row*64 + seg*2*... (u32->2B half)
      *(half8_t*)swzp(Ah, ab)      = h0;
      *(half8_t*)swzp(Ah, ab + 16) = h1;
      *(half8_t*)swzp(Al, ab)      = l0;
      *(half8_t*)swzp(Al, ab + 16) = l1;
      const int wb = (wrow<<6) + (wseg<<1);
      *(half8_t*)swzp(Bh,  wb) = wh;
      *(half8_t*)swzp(Blo, wb) = wl;
    }
    __syncthreads();                        // staged tile visible
    half8_t ah[2], al[2];
    #pragma unroll
    for(int rt=0;rt<2;++rt){
      ah[rt] = *(const half8_t*)swzp(Ah, ((wv*32 + rt*16 + frow)<<6) + fb);
      al[rt] = *(const half8_t*)swzp(Al, ((wv*32 + rt*16 + frow)<<6) + fb);
    }
    #pragma unroll
    for(int c=0;c<4;++c){
      const half8_t bh = *(const half8_t*)swzp(Bh,  ((c*16 + frow)<<6) + fb);
      const half8_t bl = *(const half8_t*)swzp(Blo, ((c*16 + frow)<<6) + fb);
      #pragma unroll
      for(int rt=0;rt<2;++rt){
        acc[rt][c] = __builtin_amdgcn_mfma_f32_16x16x32_f16(ah[rt], bh, acc[rt][c], 0, 0, 0);
        acc[rt][c] = __builtin_amdgcn_mfma_f32_16x16x32_f16(al[rt], bh, acc[rt][c], 0, 0, 0);
        acc[rt][c] = __builtin_amdgcn_mfma_f32_16x16x32_f16(ah[rt], bl, acc[rt][c], 0, 0, 0);
      }
    }
  }

  const int pcol = lane & 15;
  #pragma unroll
  for(int rt=0;rt<2;++rt){
    const int prow0 = mbase + wv*32 + rt*16 + (lane>>4)*4;
    #pragma unroll
    for(int c=0;c<4;++c){
      #pragma unroll
      for(int r=0;r<4;++r){
        const int rr = prow0 + r;
        if(rr < M)
          P[((size_t)s*NPTS + node_base + rr)*64 + c*16 + pcol] = acc[rt][c][r];
      }
    }
  }
}

// ---- combine partials: x[node*ldout+colofs+o] += sum_s P[s][node][o]
template<int S>
__global__ void k_combine(const float* __restrict__ P, float* __restrict__ x,
                          int ldout, int colofs)
{
  int idx = blockIdx.x*blockDim.x + threadIdx.x;
  if(idx >= NPTS*16) return;
  int node = idx >> 4, c4 = (idx & 15) * 4;
  float4 s = *(const float4*)(P + (size_t)node*64 + c4);
  #pragma unroll
  for(int k=1;k<S;++k){
    float4 t = *(const float4*)(P + ((size_t)k*NPTS + node)*64 + c4);
    s.x+=t.x; s.y+=t.y; s.z+=t.z; s.w+=t.w;
  }
  float* xp = x + (size_t)node*ldout + colofs + c4;
  float4 o = *(float4*)xp;
  o.x+=s.x; o.y+=s.y; o.z+=s.z; o.w+=s.w;
  *(float4*)xp = o;
}

// ---------------- dense paths ----------------
__global__ void k_dense0(const float* __restrict__ f, const float* __restrict__ dW,
                         const float* __restrict__ db, const float* __restrict__ cb0,
                         float* __restrict__ out)
{
  int idx = blockIdx.x*blockDim.x + threadIdx.x;
  if(idx >= NPTS*96) return;
  int i = idx/96, c = idx - i*96;
  if(c < 64){ out[idx] = cb0[c]; return; }
  int o = c - 64;
  float s = db[o];
  const float* row = f + (size_t)i*13;
  #pragma unroll
  for(int j=0;j<13;++j) s = fmaf(row[j], dW[j*32+o], s);
  out[idx] = s;
}

__global__ void k_dense(const float* __restrict__ in, int cin,
                        const float* __restrict__ dW, const float* __restrict__ db,
                        const float* __restrict__ cb, const float* __restrict__ resid,
                        float* __restrict__ out)
{
  int idx = blockIdx.x*blockDim.x + threadIdx.x;
  if(idx >= NPTS*64) return;
  int i = idx >> 6, o = idx & 63;
  float s = db[o] + cb[o];
  if(resid) s += resid[idx];
  const float* row = in + (size_t)i*cin;
  for(int c=0;c<cin;++c) s = fmaf(fmaxf(row[c],0.f), dW[c*64+o], s);
  out[idx] = s;
}

__global__ void k_dense3(const float* __restrict__ x2, const float* __restrict__ dW,
                         const float* __restrict__ db, const float* __restrict__ cb,
                         float* __restrict__ out)
{
  int idx = blockIdx.x*blockDim.x + threadIdx.x;
  if(idx >= NREAL*3) return;
  int i = idx/3, o = idx - i*3;
  float s = db[o] + cb[o];
  const float* row = x2 + (size_t)i*64;
  for(int c=0;c<64;++c) s = fmaf(fmaxf(row[c],0.f), dW[c*3+o], s);
  out[idx] = s * (1.f/128.f);
}

// ---------------- host ----------------
static inline size_t alup(size_t x){ return (x + 255) & ~(size_t)255; }

static inline int calc_rows(size_t bcap, int cin, int want){
  size_t perrow = (size_t)KK * cin * 4;
  size_t r = (perrow > 0) ? bcap / perrow : 0;
  if(r >= (size_t)want) return want;
  r = (r / 128) * 128;
  if(r < 128) r = 128;
  return (int)r;
}

extern "C" void kernel_launch(void* const* d_in, const int* in_sizes, int n_in,
                              void* d_out, int out_size, void* d_ws, size_t ws_size,
                              hipStream_t stream)
{
  const float* pos   = (const float*)d_in[0];
  const float* feats = (const float*)d_in[1];
  const int*   esrc  = (const int*)d_in[2];
  const int*   edst  = (const int*)d_in[3];
  const float* c0w = (const float*)d_in[4];
  const float* c0b = (const float*)d_in[5];
  const float* d0w = (const float*)d_in[6];
  const float* d0b = (const float*)d_in[7];
  const float* c1w = (const float*)d_in[8];
  const float* c1b = (const float*)d_in[9];
  const float* d1w = (const float*)d_in[10];
  const float* d1b = (const float*)d_in[11];
  const float* c2w = (const float*)d_in[12];
  const float* c2b = (const float*)d_in[13];
  const float* d2w = (const float*)d_in[14];
  const float* d2b = (const float*)d_in[15];
  const float* c3w = (const float*)d_in[16];
  const float* c3b = (const float*)d_in[17];
  const float* d3w = (const float*)d_in[18];
  const float* d3b = (const float*)d_in[19];
  float* out = (float*)d_out;

  char* w = (char*)d_ws;
  size_t off = 0;
  float* f  = (float*)(w+off); off += alup((size_t)NPTS*13*4);
  float* x0 = (float*)(w+off); off += alup((size_t)NPTS*96*4);
  float* x1 = (float*)(w+off); off += alup((size_t)NPTS*64*4);
  float* x2 = (float*)(w+off); off += alup((size_t)NPTS*64*4);
  int* row_start = (int*)(w+off); off += alup((size_t)(NPTS+1)*4);
  int* ereal = (int*)(w+off);     off += alup(16);
  float4* gw = (float4*)(w+off);  off += alup((size_t)EPAD*16);     // per-edge xy weights
  int4*  gmz = (int4*)(w+off);    off += alup((size_t)EPAD*16);     // per-edge zA+cells+dst
  float* P  = (float*)(w+off); off += alup((size_t)8*NPTS*64*4);    // split-K partials
  _Float16* whT = (_Float16*)(w+off); off += alup((size_t)64*6144*2); // W hi (transposed)
  _Float16* wlT = (_Float16*)(w+off); off += alup((size_t)64*6144*2); // W lo (transposed)
  unsigned* Fp0 = (unsigned*)(w+off); off += alup((size_t)NPTS*96*4); // packed pre-split feats (96ch)
  unsigned* Fp1 = (unsigned*)(w+off); off += alup((size_t)NPTS*64*4); // packed pre-split feats (64ch)
  unsigned* B = (unsigned*)(w+off);                                   // packed pre-split B
  size_t bcap = (ws_size > off) ? (ws_size - off) : 0;

  k_find_ereal<<<1,1,0,stream>>>(edst, ereal);
  k_csr<<<(NPTS+1+255)/256,256,0,stream>>>(esrc, ereal, row_start);
  k_build_f<<<(NPTS*13+255)/256,256,0,stream>>>(feats, f);
  k_geom<<<(EPAD+255)/256,256,0,stream>>>(pos, esrc, edst, gw, gmz);

  // ---- layer 0: x0[:,0:64] = cconv0(f)+c0b ; x0[:,64:96] = f@d0w+d0b  (chunk 8192)
  k_dense0<<<(NPTS*96+255)/256,256,0,stream>>>(f, d0w, d0b, c0b, x0);
  {
    k_cvtW<<<(64*832+255)/256,256,0,stream>>>(c0w, whT, wlT, 832);
    int rows = calc_rows(bcap, 13, 8192);
    for(int base = 0; base < NPTS; base += rows){
      int m = (NPTS - base < rows) ? (NPTS - base) : rows;
      k_scat13<<<m,128,0,stream>>>(f, gw, gmz, row_start, B, base);
      k_gemm_mfma<<<dim3((m+127)/128, 8),256,0,stream>>>(B, whT, wlT, P, m, 832, base, 4);
    }
    k_combine<8><<<(NPTS*16+255)/256,256,0,stream>>>(P, x0, 96, 0);
  }

  // ---- layer 1: x1 = cconv1(relu(x0)) + relu(x0)@d1w + d1b + c1b   (chunk 4096)
  k_dense<<<(NPTS*64+255)/256,256,0,stream>>>(x0, 96, d1w, d1b, c1b, nullptr, x1);
  {
    k_cvtW<<<(64*6144+255)/256,256,0,stream>>>(c1w, whT, wlT, 6144);
    k_cvtF<<<(NPTS*96+255)/256,256,0,stream>>>(x0, Fp0, NPTS*96);
    int rows = calc_rows(bcap, 96, 4096);
    for(int base = 0; base < NPTS; base += rows){
      int m = (NPTS - base < rows) ? (NPTS - base) : rows;
      k_scat96m<<<m,256,0,stream>>>(Fp0, gw, gmz, row_start, B, base);
      k_gemm_mfma<<<dim3((m+127)/128, 8),256,0,stream>>>(B, whT, wlT, P, m, 6144, base, 24);
    }
    k_combine<8><<<(NPTS*16+255)/256,256,0,stream>>>(P, x1, 64, 0);
  }

  // ---- layer 2: x2 = cconv2(relu(x1)) + relu(x1)@d2w + d2b + c2b + x1  (chunk 4096)
  k_dense<<<(NPTS*64+255)/256,256,0,stream>>>(x1, 64, d2w, d2b, c2b, x1, x2);
  {
    k_cvtW<<<(64*4096+255)/256,256,0,stream>>>(c2w, whT, wlT, 4096);
    k_cvtF<<<(NPTS*64+255)/256,256,0,stream>>>(x1, Fp1, NPTS*64);
    int rows = calc_rows(bcap, 64, 4096);
    for(int base = 0; base < NPTS; base += rows){
      int m = (NPTS - base < rows) ? (NPTS - base) : rows;
      k_scat64m<0><<<m,256,0,stream>>>(Fp1, gw, gmz, row_start, B, base, nullptr, nullptr);
      k_gemm_mfma<<<dim3((m+127)/128, 8),256,0,stream>>>(B, whT, wlT, P, m, 4096, base, 16);
    }
    k_combine<8><<<(NPTS*16+255)/256,256,0,stream>>>(P, x2, 64, 0);
  }

  // ---- layer 3 (fused): out = dense3 part, then scatter adds conv3 GEMV directly
  k_dense3<<<(NREAL*3+255)/256,256,0,stream>>>(x2, d3w, d3b, c3b, out);
  k_cvtF<<<(NPTS*64+255)/256,256,0,stream>>>(x2, Fp1, NPTS*64);
  k_scat64m<1><<<NPTS,256,0,stream>>>(Fp1, gw, gmz, row_start, nullptr, 0, c3w, out);
}

// Round 15
// 977.140 us; speedup vs baseline: 1.0564x; 1.0564x over previous
//
#include <hip/hip_runtime.h>
#include <math.h>

#define NPTS   20001
#define NREAL  20000
#define EPAD   1200000
#define KK     64
#define RADF   0.1125f

typedef _Float16 half8_t __attribute__((ext_vector_type(8)));
typedef float    floatx4 __attribute__((ext_vector_type(4)));

__device__ __forceinline__ float sgnf(float v){ return v>0.f ? 1.f : (v<0.f ? -1.f : 0.f); }
__device__ __forceinline__ _Float16 lo16(unsigned u){ return __builtin_bit_cast(_Float16, (unsigned short)(u & 0xffffu)); }
__device__ __forceinline__ _Float16 hi16(unsigned u){ return __builtin_bit_cast(_Float16, (unsigned short)(u >> 16)); }
// deterministic fp32 -> packed f16 hi/lo split (hi in low 16 bits). Producer-side packing
// is BIT-IDENTICAL to the GEMM doing the split itself, just hoisted.
__device__ __forceinline__ unsigned packf(float v){
  _Float16 h = (_Float16)v;
  _Float16 l = (_Float16)(v - (float)h);
  return (unsigned)__builtin_bit_cast(unsigned short, h)
       | ((unsigned)__builtin_bit_cast(unsigned short, l) << 16);
}

// byte-offset XOR swizzle for [rows][32]-half (64B-row) LDS tiles.
__device__ __forceinline__ void* swzp(void* base, int byteoff){
  return (void*)((char*)base + (byteoff ^ (((byteoff >> 6) & 7) << 4)));
}
__device__ __forceinline__ const void* swzp(const void* base, int byteoff){
  return (const void*)((const char*)base + (byteoff ^ (((byteoff >> 6) & 7) << 4)));
}

// ---------------- CSR build (edge_src is sorted; pad edges have dst==NREAL) ----------------
__global__ void k_find_ereal(const int* __restrict__ dst, int* __restrict__ ereal){
  int lo=0, hi=EPAD;
  while(lo<hi){ int mid=(lo+hi)>>1; if(dst[mid]==NREAL) hi=mid; else lo=mid+1; }
  *ereal = lo;
}

__global__ void k_csr(const int* __restrict__ src, const int* __restrict__ erealp,
                      int* __restrict__ row_start){
  int i = blockIdx.x*blockDim.x + threadIdx.x;
  if(i > NPTS) return;
  int E = *erealp;
  int lo=0, hi=E;
  while(lo<hi){ int mid=(lo+hi)>>1; if(src[mid] < i) lo=mid+1; else hi=mid; }
  row_start[i] = lo;
}

__global__ void k_build_f(const float* __restrict__ feats, float* __restrict__ f){
  int idx = blockIdx.x*blockDim.x + threadIdx.x;
  if(idx >= NPTS*13) return;
  int i = idx/13, c = idx - i*13;
  f[idx] = (c==0) ? 1.f : feats[i*12 + (c-1)];
}

// ---- feature pre-pass: relu + split + pack, once per layer.
__global__ void k_cvtF(const float* __restrict__ x, unsigned* __restrict__ Fp, int total){
  int idx = blockIdx.x*blockDim.x + threadIdx.x;
  if(idx >= total) return;
  Fp[idx] = packf(fmaxf(x[idx], 0.f));
}

// ---------------- per-edge geometry (exact port of ball_to_cube + window) ----------------
__device__ __forceinline__ void edge_geom(float ox, float oy, float oz,
                                          float& win, float& t0, float& t1, float& t2, int& f0p){
  const float eps = 1e-9f;
  float sq = ox*ox + oy*oy + oz*oz;
  float u = 1.f - sq;
  win = fminf(fmaxf(u*u*u, 0.f), 1.f);
  float norm = sqrtf(sq + eps);
  float rxy2 = ox*ox + oy*oy;
  bool polar = (1.25f*oz*oz > rxy2);
  float s_p = sqrtf(3.f*norm/(norm + fabsf(oz) + eps));
  float s_n = norm / sqrtf(rxy2 + eps);
  float s = polar ? s_p : s_n;
  float xc = ox*s, yc = oy*s;
  float zc = polar ? sgnf(oz)*norm : 1.5f*oz;
  if(sq < 1e-12f){ xc = 0.f; yc = 0.f; zc = 0.f; }
  float r = sqrtf(xc*xc + yc*yc + eps);
  bool c1 = fabsf(xc) >= fabsf(yc);
  float xs = (fabsf(xc) < eps) ? eps : xc;
  float ys = (fabsf(yc) < eps) ? eps : yc;
  const float fop = 1.2732395447351628f; // float32(4/pi)
  float a = c1 ? sgnf(xc)*r : sgnf(yc)*r*fop*atanf(xc/ys);
  float b = c1 ? sgnf(xc)*r*fop*atanf(yc/xs) : sgnf(yc)*r;
  if(xc*xc + yc*yc < 1e-12f){ a = 0.f; b = 0.f; }
  float g0 = fminf(fmaxf((a *0.5f+0.5f)*3.f, 0.f), 3.f);
  float g1 = fminf(fmaxf((b *0.5f+0.5f)*3.f, 0.f), 3.f);
  float g2 = fminf(fmaxf((zc*0.5f+0.5f)*3.f, 0.f), 3.f);
  float f00 = floorf(g0), f01 = floorf(g1), f02 = floorf(g2);
  t0 = g0 - f00; t1 = g1 - f01; t2 = g2 - f02;
  f0p = (int)f00 | ((int)f01 << 2) | ((int)f02 << 4);
}

// ---- k_geom: per-edge staged data, computed ONCE (shared by all 4 scatter layers).
__global__ __launch_bounds__(256) void k_geom(const float* __restrict__ pos,
    const int* __restrict__ esrc, const int* __restrict__ edst,
    float4* __restrict__ gw, int4* __restrict__ gmz)
{
  int e = blockIdx.x*blockDim.x + threadIdx.x;
  if(e >= EPAD) return;
  const int sn = esrc[e], d = edst[e];
  const float ox = (pos[d*3+0]-pos[sn*3+0])/RADF;
  const float oy = (pos[d*3+1]-pos[sn*3+1])/RADF;
  const float oz = (pos[d*3+2]-pos[sn*3+2])/RADF;
  float win, t0, t1, t2; int f0p;
  edge_geom(ox, oy, oz, win, t0, t1, t2, f0p);
  const int i0 = f0p & 3, i1 = (f0p>>2) & 3, i2 = f0p >> 4;
  const int X0 = i0 << 4, X1 = ((i0+1)&3) << 4;
  const int Y0 = i1 << 2, Y1 = ((i1+1)&3) << 2;
  const int Z0 = i2, Z1 = (i2+1) & 3;
  const float wx0 = win*(1.f-t0), wx1 = win*t0;
  const float wy0 = 1.f-t1, wy1 = t1;
  const float wz0 = 1.f-t2, wz1 = t2;
  gw[e] = make_float4(wx0*wy0, wx0*wy1, wx1*wy0, wx1*wy1);
  const int p0 = Z0 & 1;
  const float zA = p0 ? wz1 : wz0;                  // weight for parity-0 (even z) cell
  const int   cA = p0 ? Z1 : Z0;                    // even-z cell
  const int   cB = p0 ? Z0 : Z1;                    // odd-z cell
  const int cells0 = (X0|Y0|cA) | ((X0|Y1|cA)<<8) | ((X1|Y0|cA)<<16) | ((X1|Y1|cA)<<24);
  const int cells1 = (X0|Y0|cB) | ((X0|Y1|cB)<<8) | ((X1|Y0|cB)<<16) | ((X1|Y1|cB)<<24);
  gmz[e] = make_int4(__float_as_int(zA), cells0, cells1, d);
}

// ------- MFMA scatter CIN=64 (r12 structure, measured 123-127us), packed-B epilogue.
template<int OUT3>
__global__ __launch_bounds__(256) void k_scat64m(
    const unsigned* __restrict__ Fp, const float4* __restrict__ gw,
    const int4* __restrict__ gmz, const int* __restrict__ row_start,
    unsigned* __restrict__ B, int node_base,
    const float* __restrict__ W3, float* __restrict__ out)
{
  __shared__ __align__(128) _Float16 Wh[64*32];
  __shared__ __align__(128) _Float16 Wl[64*32];
  __shared__ __align__(128) _Float16 Fh[64*32];
  __shared__ __align__(128) _Float16 Fl[64*32];
  __shared__ __align__(16) float4 Sq[32];
  __shared__ __align__(16) int4   Smd[32];
  __shared__ float red[16];

  const int tid  = threadIdx.x;
  const int node = node_base + blockIdx.x;
  const int wv   = tid >> 6;
  const int lane = tid & 63;
  const int frow = lane & 15;
  const int fb   = (lane >> 4) << 4;   // frag col byte offset

  floatx4 acc[4];
  #pragma unroll
  for(int nt=0;nt<4;++nt){ acc[nt][0]=0.f; acc[nt][1]=0.f; acc[nt][2]=0.f; acc[nt][3]=0.f; }

  half8_t hz;
  #pragma unroll
  for(int q8=0;q8<8;++q8) hz[q8] = (_Float16)0;

  const int e0 = row_start[node], e1 = row_start[node+1];

  for(int eb = e0; eb < e1; eb += 32){
    const int n = (e1 - eb < 32) ? (e1 - eb) : 32;
    __syncthreads();
    if(wv == 0){
      if(lane < 32){
        int ei = eb + lane; if(ei >= e1) ei = e1 - 1;
        Sq[lane]  = gw[ei];
        Smd[lane] = gmz[ei];
      }
    } else {
      for(int j = tid - 64; j < 512; j += 192){
        if(j < 256) ((half8_t*)Wh)[j]       = hz;
        else        ((half8_t*)Wl)[j - 256] = hz;
      }
    }
    __syncthreads();
    {
      half8_t hreg, lreg;
      #pragma unroll
      for(int j=0;j<8;++j){
        const int dst = Smd[wv*8 + j].w;
        const unsigned u = Fp[(size_t)dst*64 + lane];
        hreg[j] = lo16(u);
        lreg[j] = hi16(u);
      }
      *(half8_t*)swzp(Fh, (lane<<6) + (wv<<4)) = hreg;
      *(half8_t*)swzp(Fl, (lane<<6) + (wv<<4)) = lreg;
    }
    if(lane < 8){
      const int ei = wv*8 + lane;
      if(ei < n){
        const float4 q  = Sq[ei];
        const int4   md = Smd[ei];
        const float zA = __int_as_float(md.x), zB = 1.f - zA;
        #pragma unroll
        for(int t=0;t<8;++t){
          const int   cells = (t < 4) ? md.y : md.z;
          const float zz    = (t < 4) ? zA : zB;
          const int   cell  = (cells >> ((t & 3) * 8)) & 255;
          const float qq    = ((t&3)==0) ? q.x : ((t&3)==1) ? q.y : ((t&3)==2) ? q.z : q.w;
          const float wgt   = qq * zz;
          const _Float16 h  = (_Float16)wgt;
          *(_Float16*)swzp(Wh, (cell<<6) + (ei<<1)) = h;
          *(_Float16*)swzp(Wl, (cell<<6) + (ei<<1)) = (_Float16)(wgt - (float)h);
        }
      }
    }
    __syncthreads();
    const half8_t ah = *(const half8_t*)swzp(Wh, ((wv*16 + frow)<<6) + fb);
    const half8_t al = *(const half8_t*)swzp(Wl, ((wv*16 + frow)<<6) + fb);
    #pragma unroll
    for(int nt=0; nt<4; ++nt){
      const half8_t bh = *(const half8_t*)swzp(Fh, ((nt*16 + frow)<<6) + fb);
      const half8_t bl = *(const half8_t*)swzp(Fl, ((nt*16 + frow)<<6) + fb);
      acc[nt] = __builtin_amdgcn_mfma_f32_16x16x32_f16(ah, bh, acc[nt], 0, 0, 0);
      acc[nt] = __builtin_amdgcn_mfma_f32_16x16x32_f16(al, bh, acc[nt], 0, 0, 0);
      acc[nt] = __builtin_amdgcn_mfma_f32_16x16x32_f16(ah, bl, acc[nt], 0, 0, 0);
    }
  }

  if(!OUT3){
    unsigned* Bg = B + (size_t)blockIdx.x*4096;
    #pragma unroll
    for(int nt=0;nt<4;++nt)
      #pragma unroll
      for(int r=0;r<4;++r){
        const int cell = wv*16 + (lane>>4)*4 + r;
        Bg[cell*64 + nt*16 + (lane&15)] = packf(acc[nt][r]);
      }
  } else {
    float s0=0.f, s1=0.f, s2=0.f;
    #pragma unroll
    for(int nt=0;nt<4;++nt){
      #pragma unroll
      for(int r=0;r<4;++r){
        const int cell = wv*16 + (lane>>4)*4 + r;
        const int j3   = (cell*64 + nt*16 + (lane&15)) * 3;
        const float v  = acc[nt][r];
        s0 = fmaf(v, W3[j3+0], s0);
        s1 = fmaf(v, W3[j3+1], s1);
        s2 = fmaf(v, W3[j3+2], s2);
      }
    }
    #pragma unroll
    for(int off = 32; off > 0; off >>= 1){
      s0 += __shfl_down(s0, off);
      s1 += __shfl_down(s1, off);
      s2 += __shfl_down(s2, off);
    }
    if(lane == 0){
      red[wv*4+0] = s0; red[wv*4+1] = s1; red[wv*4+2] = s2;
    }
    __syncthreads();
    if(tid == 0 && node < NREAL){
      out[node*3+0] += (red[0]+red[4]+red[8] +red[12])*(1.f/128.f);
      out[node*3+1] += (red[1]+red[5]+red[9] +red[13])*(1.f/128.f);
      out[node*3+2] += (red[2]+red[6]+red[10]+red[14])*(1.f/128.f);
    }
  }
}

// ------- MFMA scatter CIN=96 (r12 structure), packed-B epilogue.
__global__ __launch_bounds__(256) void k_scat96m(
    const unsigned* __restrict__ Fp, const float4* __restrict__ gw,
    const int4* __restrict__ gmz, const int* __restrict__ row_start,
    unsigned* __restrict__ B, int node_base)
{
  __shared__ __align__(128) _Float16 Wh[64*32];
  __shared__ __align__(128) _Float16 Wl[64*32];
  __shared__ __align__(128) _Float16 Fh[96*32];
  __shared__ __align__(128) _Float16 Fl[96*32];
  __shared__ __align__(16) float4 Sq[32];
  __shared__ __align__(16) int4   Smd[32];

  const int tid  = threadIdx.x;
  const int node = node_base + blockIdx.x;
  const int wv   = tid >> 6;
  const int lane = tid & 63;
  const int frow = lane & 15;
  const int fb   = (lane >> 4) << 4;

  floatx4 acc[6];
  #pragma unroll
  for(int nt=0;nt<6;++nt){ acc[nt][0]=0.f; acc[nt][1]=0.f; acc[nt][2]=0.f; acc[nt][3]=0.f; }

  half8_t hz;
  #pragma unroll
  for(int q8=0;q8<8;++q8) hz[q8] = (_Float16)0;

  const int e0 = row_start[node], e1 = row_start[node+1];

  for(int eb = e0; eb < e1; eb += 32){
    const int n = (e1 - eb < 32) ? (e1 - eb) : 32;
    __syncthreads();
    if(wv == 0){
      if(lane < 32){
        int ei = eb + lane; if(ei >= e1) ei = e1 - 1;
        Sq[lane]  = gw[ei];
        Smd[lane] = gmz[ei];
      }
    } else {
      for(int j = tid - 64; j < 512; j += 192){
        if(j < 256) ((half8_t*)Wh)[j]       = hz;
        else        ((half8_t*)Wl)[j - 256] = hz;
      }
    }
    __syncthreads();
    {
      half8_t h0, l0, h1, l1;
      #pragma unroll
      for(int j=0;j<8;++j){
        const int dst = Smd[wv*8 + j].w;
        const unsigned u = Fp[(size_t)dst*96 + lane];
        h0[j] = lo16(u);
        l0[j] = hi16(u);
        if(lane < 32){
          const unsigned u2 = Fp[(size_t)dst*96 + 64 + lane];
          h1[j] = lo16(u2);
          l1[j] = hi16(u2);
        }
      }
      *(half8_t*)swzp(Fh, (lane<<6) + (wv<<4)) = h0;
      *(half8_t*)swzp(Fl, (lane<<6) + (wv<<4)) = l0;
      if(lane < 32){
        *(half8_t*)swzp(Fh, ((64+lane)<<6) + (wv<<4)) = h1;
        *(half8_t*)swzp(Fl, ((64+lane)<<6) + (wv<<4)) = l1;
      }
    }
    if(lane < 8){
      const int ei = wv*8 + lane;
      if(ei < n){
        const float4 q  = Sq[ei];
        const int4   md = Smd[ei];
        const float zA = __int_as_float(md.x), zB = 1.f - zA;
        #pragma unroll
        for(int t=0;t<8;++t){
          const int   cells = (t < 4) ? md.y : md.z;
          const float zz    = (t < 4) ? zA : zB;
          const int   cell  = (cells >> ((t & 3) * 8)) & 255;
          const float qq    = ((t&3)==0) ? q.x : ((t&3)==1) ? q.y : ((t&3)==2) ? q.z : q.w;
          const float wgt   = qq * zz;
          const _Float16 h  = (_Float16)wgt;
          *(_Float16*)swzp(Wh, (cell<<6) + (ei<<1)) = h;
          *(_Float16*)swzp(Wl, (cell<<6) + (ei<<1)) = (_Float16)(wgt - (float)h);
        }
      }
    }
    __syncthreads();
    const half8_t ah = *(const half8_t*)swzp(Wh, ((wv*16 + frow)<<6) + fb);
    const half8_t al = *(const half8_t*)swzp(Wl, ((wv*16 + frow)<<6) + fb);
    #pragma unroll
    for(int nt=0; nt<6; ++nt){
      const half8_t bh = *(const half8_t*)swzp(Fh, ((nt*16 + frow)<<6) + fb);
      const half8_t bl = *(const half8_t*)swzp(Fl, ((nt*16 + frow)<<6) + fb);
      acc[nt] = __builtin_amdgcn_mfma_f32_16x16x32_f16(ah, bh, acc[nt], 0, 0, 0);
      acc[nt] = __builtin_amdgcn_mfma_f32_16x16x32_f16(al, bh, acc[nt], 0, 0, 0);
      acc[nt] = __builtin_amdgcn_mfma_f32_16x16x32_f16(ah, bl, acc[nt], 0, 0, 0);
    }
  }

  unsigned* Bg = B + (size_t)blockIdx.x*6144;
  #pragma unroll
  for(int nt=0;nt<6;++nt)
    #pragma unroll
    for(int r=0;r<4;++r){
      const int cell = wv*16 + (lane>>4)*4 + r;
      Bg[cell*96 + nt*16 + (lane&15)] = packf(acc[nt][r]);
    }
}

// ------- scatter CIN=13 (RMW form), packed-B epilogue -------------------------------------
__global__ __launch_bounds__(128) void k_scat13(
    const float* __restrict__ feat, const float4* __restrict__ gw,
    const int4* __restrict__ gmz, const int* __restrict__ row_start,
    unsigned* __restrict__ B, int node_base)
{
  constexpr int CIN = 13, BSZ = KK*CIN, ESW = 4, CSTRIDE = BSZ + 8;
  __shared__ __align__(16) float Bl[ESW*CSTRIDE];
  const int tid  = threadIdx.x;
  const int node = node_base + blockIdx.x;

  for(int j = tid; j < ESW*CSTRIDE; j += 128) Bl[j] = 0.f;

  const int e0 = row_start[node], e1 = row_start[node+1];
  const int wv   = tid >> 6;
  const int lane = tid & 63;
  const int slot = lane >> 4;
  const int c    = lane & 15;
  const bool act = (c < CIN);
  float* Bp = Bl + slot*CSTRIDE;
  __syncthreads();

  if(act){
    for(int e = e0 + slot; e < e1; e += ESW){
      const float4 q  = gw[e];
      const int4   md = gmz[e];
      const float zA = __int_as_float(md.x);
      const float z  = wv ? (1.f - zA) : zA;
      const int   cp = wv ? md.z : md.y;
      float v = feat[(size_t)md.w*CIN + c] * z;
      const int b0 = ( cp        & 255)*CIN + c;
      const int b1 = ((cp >> 8)  & 255)*CIN + c;
      const int b2 = ((cp >> 16) & 255)*CIN + c;
      const int b3 = (((unsigned)cp) >> 24)*CIN + c;
      float o0 = Bp[b0], o1 = Bp[b1], o2 = Bp[b2], o3 = Bp[b3];
      o0 = fmaf(q.x, v, o0); o1 = fmaf(q.y, v, o1);
      o2 = fmaf(q.z, v, o2); o3 = fmaf(q.w, v, o3);
      Bp[b0] = o0; Bp[b1] = o1; Bp[b2] = o2; Bp[b3] = o3;
    }
  }
  __syncthreads();

  unsigned* Bg = B + (size_t)blockIdx.x*BSZ;
  for(int j = tid*4; j < BSZ; j += 512){
    float4 a = *(const float4*)&Bl[j];
    #pragma unroll
    for(int k = 1; k < ESW; ++k){
      const float4 t = *(const float4*)&Bl[k*CSTRIDE + j];
      a.x += t.x; a.y += t.y; a.z += t.z; a.w += t.w;
    }
    uint4 o;
    o.x = packf(a.x); o.y = packf(a.y); o.z = packf(a.z); o.w = packf(a.w);
    *(uint4*)&Bg[j] = o;
  }
}

// ---- W pre-pass: transpose + split fp32 -> f16 hi/lo.  WhT/WlT layout [64 cols][Kd k]
__global__ void k_cvtW(const float* __restrict__ W, _Float16* __restrict__ WhT,
                       _Float16* __restrict__ WlT, int Kd)
{
  int idx = blockIdx.x*blockDim.x + threadIdx.x;
  if(idx >= 64*Kd) return;
  int o = idx / Kd, k = idx - o*Kd;
  float w = W[(size_t)k*64 + o];
  _Float16 h = (_Float16)w;
  WhT[idx] = h;
  WlT[idx] = (_Float16)(w - (float)h);
}

// ---- MFMA GEMM v3: r12's proven M=64 tile + packed pre-split A reads (no fp32 loads,
// no split VALU). r13's M=128 variant REGRESSED (6 blk/CU, reg pressure) — reverted.
__global__ __launch_bounds__(256) void k_gemm_mfma(
    const unsigned* __restrict__ Ap, const _Float16* __restrict__ WhT,
    const _Float16* __restrict__ WlT, float* __restrict__ P,
    int M, int Kd, int node_base, int ksteps_per)
{
  __shared__ __align__(128) _Float16 Ah[64*32];
  __shared__ __align__(128) _Float16 Al[64*32];
  __shared__ __align__(128) _Float16 Bh[64*32];
  __shared__ __align__(128) _Float16 Blo[64*32];
  const int tid = threadIdx.x;
  const int mbase = blockIdx.x * 64;
  const int s = blockIdx.y;
  const int kt0 = s * ksteps_per * 32;
  const int kt1 = min(Kd, kt0 + ksteps_per*32);
  const int wv = tid >> 6, lane = tid & 63;
  const int row  = tid >> 2;          // staging row (A row / W col), 0..63
  const int useg = (tid & 3) * 8;     // u32 seg (8 u32 per thread) within 32-wide tile
  const int sb   = (tid & 3) << 4;    // staging byte col (16B per thread per buf)
  const int frow = lane & 15;
  const int fb   = (lane >> 4) << 4;  // frag byte col

  floatx4 acc[4];
  #pragma unroll
  for(int c=0;c<4;++c){ acc[c][0]=0.f; acc[c][1]=0.f; acc[c][2]=0.f; acc[c][3]=0.f; }

  const int grow = mbase + row;
  const unsigned* Arow = (grow < M) ? (Ap + (size_t)grow*Kd) : nullptr;
  const _Float16* WhRow = WhT + (size_t)row*Kd;
  const _Float16* WlRow = WlT + (size_t)row*Kd;

  for(int kt = kt0; kt < kt1; kt += 32){
    unsigned au[8];
    if(Arow){
      *(uint4*)&au[0] = *(const uint4*)(Arow + kt + useg);
      *(uint4*)&au[4] = *(const uint4*)(Arow + kt + useg + 4);
    } else {
      #pragma unroll
      for(int j=0;j<8;++j) au[j] = 0u;
    }
    half8_t hv, lv;
    #pragma unroll
    for(int j=0;j<8;++j){
      hv[j] = lo16(au[j]);
      lv[j] = hi16(au[j]);
    }
    half8_t wh = *(const half8_t*)(WhRow + kt + useg);
    half8_t wl = *(const half8_t*)(WlRow + kt + useg);
    __syncthreads();                        // previous iter's frag reads complete
    *(half8_t*)swzp(Ah,  (row<<6) + sb) = hv;
    *(half8_t*)swzp(Al,  (row<<6) + sb) = lv;
    *(half8_t*)swzp(Bh,  (row<<6) + sb) = wh;
    *(half8_t*)swzp(Blo, (row<<6) + sb) = wl;
    __syncthreads();                        // staged tile visible
    const half8_t ah = *(const half8_t*)swzp(Ah, ((wv*16 + frow)<<6) + fb);
    const half8_t al = *(const half8_t*)swzp(Al, ((wv*16 + frow)<<6) + fb);
    #pragma unroll
    for(int c=0;c<4;++c){
      const half8_t bh = *(const half8_t*)swzp(Bh,  ((c*16 + frow)<<6) + fb);
      const half8_t bl = *(const half8_t*)swzp(Blo, ((c*16 + frow)<<6) + fb);
      acc[c] = __builtin_amdgcn_mfma_f32_16x16x32_f16(ah, bh, acc[c], 0, 0, 0);
      acc[c] = __builtin_amdgcn_mfma_f32_16x16x32_f16(al, bh, acc[c], 0, 0, 0);
      acc[c] = __builtin_amdgcn_mfma_f32_16x16x32_f16(ah, bl, acc[c], 0, 0, 0);
    }
  }

  const int prow0 = mbase + wv*16 + (lane>>4)*4;
  const int pcol  = lane & 15;
  #pragma unroll
  for(int c=0;c<4;++c){
    #pragma unroll
    for(int r=0;r<4;++r){
      const int rr = prow0 + r;
      if(rr < M)
        P[((size_t)s*NPTS + node_base + rr)*64 + c*16 + pcol] = acc[c][r];
    }
  }
}

// ---- combine partials: x[node*ldout+colofs+o] += sum_s P[s][node][o]
template<int S>
__global__ void k_combine(const float* __restrict__ P, float* __restrict__ x,
                          int ldout, int colofs)
{
  int idx = blockIdx.x*blockDim.x + threadIdx.x;
  if(idx >= NPTS*16) return;
  int node = idx >> 4, c4 = (idx & 15) * 4;
  float4 s = *(const float4*)(P + (size_t)node*64 + c4);
  #pragma unroll
  for(int k=1;k<S;++k){
    float4 t = *(const float4*)(P + ((size_t)k*NPTS + node)*64 + c4);
    s.x+=t.x; s.y+=t.y; s.z+=t.z; s.w+=t.w;
  }
  float* xp = x + (size_t)node*ldout + colofs + c4;
  float4 o = *(float4*)xp;
  o.x+=s.x; o.y+=s.y; o.z+=s.z; o.w+=s.w;
  *(float4*)xp = o;
}

// ---------------- dense paths ----------------
__global__ void k_dense0(const float* __restrict__ f, const float* __restrict__ dW,
                         const float* __restrict__ db, const float* __restrict__ cb0,
                         float* __restrict__ out)
{
  int idx = blockIdx.x*blockDim.x + threadIdx.x;
  if(idx >= NPTS*96) return;
  int i = idx/96, c = idx - i*96;
  if(c < 64){ out[idx] = cb0[c]; return; }
  int o = c - 64;
  float s = db[o];
  const float* row = f + (size_t)i*13;
  #pragma unroll
  for(int j=0;j<13;++j) s = fmaf(row[j], dW[j*32+o], s);
  out[idx] = s;
}

__global__ void k_dense(const float* __restrict__ in, int cin,
                        const float* __restrict__ dW, const float* __restrict__ db,
                        const float* __restrict__ cb, const float* __restrict__ resid,
                        float* __restrict__ out)
{
  int idx = blockIdx.x*blockDim.x + threadIdx.x;
  if(idx >= NPTS*64) return;
  int i = idx >> 6, o = idx & 63;
  float s = db[o] + cb[o];
  if(resid) s += resid[idx];
  const float* row = in + (size_t)i*cin;
  for(int c=0;c<cin;++c) s = fmaf(fmaxf(row[c],0.f), dW[c*64+o], s);
  out[idx] = s;
}

__global__ void k_dense3(const float* __restrict__ x2, const float* __restrict__ dW,
                         const float* __restrict__ db, const float* __restrict__ cb,
                         float* __restrict__ out)
{
  int idx = blockIdx.x*blockDim.x + threadIdx.x;
  if(idx >= NREAL*3) return;
  int i = idx/3, o = idx - i*3;
  float s = db[o] + cb[o];
  const float* row = x2 + (size_t)i*64;
  for(int c=0;c<64;++c) s = fmaf(fmaxf(row[c],0.f), dW[c*3+o], s);
  out[idx] = s * (1.f/128.f);
}

// ---------------- host ----------------
static inline size_t alup(size_t x){ return (x + 255) & ~(size_t)255; }

static inline int calc_rows(size_t bcap, int cin, int want){
  size_t perrow = (size_t)KK * cin * 4;
  size_t r = (perrow > 0) ? bcap / perrow : 0;
  if(r >= (size_t)want) return want;
  r = (r / 128) * 128;
  if(r < 128) r = 128;
  return (int)r;
}

extern "C" void kernel_launch(void* const* d_in, const int* in_sizes, int n_in,
                              void* d_out, int out_size, void* d_ws, size_t ws_size,
                              hipStream_t stream)
{
  const float* pos   = (const float*)d_in[0];
  const float* feats = (const float*)d_in[1];
  const int*   esrc  = (const int*)d_in[2];
  const int*   edst  = (const int*)d_in[3];
  const float* c0w = (const float*)d_in[4];
  const float* c0b = (const float*)d_in[5];
  const float* d0w = (const float*)d_in[6];
  const float* d0b = (const float*)d_in[7];
  const float* c1w = (const float*)d_in[8];
  const float* c1b = (const float*)d_in[9];
  const float* d1w = (const float*)d_in[10];
  const float* d1b = (const float*)d_in[11];
  const float* c2w = (const float*)d_in[12];
  const float* c2b = (const float*)d_in[13];
  const float* d2w = (const float*)d_in[14];
  const float* d2b = (const float*)d_in[15];
  const float* c3w = (const float*)d_in[16];
  const float* c3b = (const float*)d_in[17];
  const float* d3w = (const float*)d_in[18];
  const float* d3b = (const float*)d_in[19];
  float* out = (float*)d_out;

  char* w = (char*)d_ws;
  size_t off = 0;
  float* f  = (float*)(w+off); off += alup((size_t)NPTS*13*4);
  float* x0 = (float*)(w+off); off += alup((size_t)NPTS*96*4);
  float* x1 = (float*)(w+off); off += alup((size_t)NPTS*64*4);
  float* x2 = (float*)(w+off); off += alup((size_t)NPTS*64*4);
  int* row_start = (int*)(w+off); off += alup((size_t)(NPTS+1)*4);
  int* ereal = (int*)(w+off);     off += alup(16);
  float4* gw = (float4*)(w+off);  off += alup((size_t)EPAD*16);     // per-edge xy weights
  int4*  gmz = (int4*)(w+off);    off += alup((size_t)EPAD*16);     // per-edge zA+cells+dst
  float* P  = (float*)(w+off); off += alup((size_t)8*NPTS*64*4);    // split-K partials
  _Float16* whT = (_Float16*)(w+off); off += alup((size_t)64*6144*2); // W hi (transposed)
  _Float16* wlT = (_Float16*)(w+off); off += alup((size_t)64*6144*2); // W lo (transposed)
  unsigned* Fp0 = (unsigned*)(w+off); off += alup((size_t)NPTS*96*4); // packed pre-split feats (96ch)
  unsigned* Fp1 = (unsigned*)(w+off); off += alup((size_t)NPTS*64*4); // packed pre-split feats (64ch)
  unsigned* B = (unsigned*)(w+off);                                   // packed pre-split B
  size_t bcap = (ws_size > off) ? (ws_size - off) : 0;

  k_find_ereal<<<1,1,0,stream>>>(edst, ereal);
  k_csr<<<(NPTS+1+255)/256,256,0,stream>>>(esrc, ereal, row_start);
  k_build_f<<<(NPTS*13+255)/256,256,0,stream>>>(feats, f);
  k_geom<<<(EPAD+255)/256,256,0,stream>>>(pos, esrc, edst, gw, gmz);

  // ---- layer 0: x0[:,0:64] = cconv0(f)+c0b ; x0[:,64:96] = f@d0w+d0b  (chunk 8192)
  k_dense0<<<(NPTS*96+255)/256,256,0,stream>>>(f, d0w, d0b, c0b, x0);
  {
    k_cvtW<<<(64*832+255)/256,256,0,stream>>>(c0w, whT, wlT, 832);
    int rows = calc_rows(bcap, 13, 8192);
    for(int base = 0; base < NPTS; base += rows){
      int m = (NPTS - base < rows) ? (NPTS - base) : rows;
      k_scat13<<<m,128,0,stream>>>(f, gw, gmz, row_start, B, base);
      k_gemm_mfma<<<dim3((m+63)/64, 8),256,0,stream>>>(B, whT, wlT, P, m, 832, base, 4);
    }
    k_combine<8><<<(NPTS*16+255)/256,256,0,stream>>>(P, x0, 96, 0);
  }

  // ---- layer 1: x1 = cconv1(relu(x0)) + relu(x0)@d1w + d1b + c1b   (chunk 4096)
  k_dense<<<(NPTS*64+255)/256,256,0,stream>>>(x0, 96, d1w, d1b, c1b, nullptr, x1);
  {
    k_cvtW<<<(64*6144+255)/256,256,0,stream>>>(c1w, whT, wlT, 6144);
    k_cvtF<<<(NPTS*96+255)/256,256,0,stream>>>(x0, Fp0, NPTS*96);
    int rows = calc_rows(bcap, 96, 4096);
    for(int base = 0; base < NPTS; base += rows){
      int m = (NPTS - base < rows) ? (NPTS - base) : rows;
      k_scat96m<<<m,256,0,stream>>>(Fp0, gw, gmz, row_start, B, base);
      k_gemm_mfma<<<dim3((m+63)/64, 8),256,0,stream>>>(B, whT, wlT, P, m, 6144, base, 24);
    }
    k_combine<8><<<(NPTS*16+255)/256,256,0,stream>>>(P, x1, 64, 0);
  }

  // ---- layer 2: x2 = cconv2(relu(x1)) + relu(x1)@d2w + d2b + c2b + x1  (chunk 4096)
  k_dense<<<(NPTS*64+255)/256,256,0,stream>>>(x1, 64, d2w, d2b, c2b, x1, x2);
  {
    k_cvtW<<<(64*4096+255)/256,256,0,stream>>>(c2w, whT, wlT, 4096);
    k_cvtF<<<(NPTS*64+255)/256,256,0,stream>>>(x1, Fp1, NPTS*64);
    int rows = calc_rows(bcap, 64, 4096);
    for(int base = 0; base < NPTS; base += rows){
      int m = (NPTS - base < rows) ? (NPTS - base) : rows;
      k_scat64m<0><<<m,256,0,stream>>>(Fp1, gw, gmz, row_start, B, base, nullptr, nullptr);
      k_gemm_mfma<<<dim3((m+63)/64, 8),256,0,stream>>>(B, whT, wlT, P, m, 4096, base, 16);
    }
    k_combine<8><<<(NPTS*16+255)/256,256,0,stream>>>(P, x2, 64, 0);
  }

  // ---- layer 3 (fused): out = dense3 part, then scatter adds conv3 GEMV directly
  k_dense3<<<(NREAL*3+255)/256,256,0,stream>>>(x2, d3w, d3b, c3b, out);
  k_cvtF<<<(NPTS*64+255)/256,256,0,stream>>>(x2, Fp1, NPTS*64);
  k_scat64m<1><<<NPTS,256,0,stream>>>(Fp1, gw, gmz, row_start, nullptr, 0, c3w, out);
}

// Round 16
// 883.889 us; speedup vs baseline: 1.1679x; 1.1055x over previous
//
#include <hip/hip_runtime.h>
#include <math.h>

#define NPTS   20001
#define NREAL  20000
#define EPAD   1200000
#define KK     64
#define RADF   0.1125f

typedef _Float16 half8_t __attribute__((ext_vector_type(8)));
typedef float    floatx4 __attribute__((ext_vector_type(4)));

__device__ __forceinline__ float sgnf(float v){ return v>0.f ? 1.f : (v<0.f ? -1.f : 0.f); }
__device__ __forceinline__ _Float16 lo16(unsigned u){ return __builtin_bit_cast(_Float16, (unsigned short)(u & 0xffffu)); }
__device__ __forceinline__ _Float16 hi16(unsigned u){ return __builtin_bit_cast(_Float16, (unsigned short)(u >> 16)); }
// deterministic fp32 -> packed f16 hi/lo split (hi in low 16 bits).
__device__ __forceinline__ unsigned packf(float v){
  _Float16 h = (_Float16)v;
  _Float16 l = (_Float16)(v - (float)h);
  return (unsigned)__builtin_bit_cast(unsigned short, h)
       | ((unsigned)__builtin_bit_cast(unsigned short, l) << 16);
}

// byte-offset XOR swizzle for [rows][32]-half (64B-row) LDS tiles.
__device__ __forceinline__ void* swzp(void* base, int byteoff){
  return (void*)((char*)base + (byteoff ^ (((byteoff >> 6) & 7) << 4)));
}
__device__ __forceinline__ const void* swzp(const void* base, int byteoff){
  return (const void*)((const char*)base + (byteoff ^ (((byteoff >> 6) & 7) << 4)));
}

// ---------------- CSR build (edge_src is sorted; pad edges have dst==NREAL) ----------------
__global__ void k_find_ereal(const int* __restrict__ dst, int* __restrict__ ereal){
  int lo=0, hi=EPAD;
  while(lo<hi){ int mid=(lo+hi)>>1; if(dst[mid]==NREAL) hi=mid; else lo=mid+1; }
  *ereal = lo;
}

__global__ void k_csr(const int* __restrict__ src, const int* __restrict__ erealp,
                      int* __restrict__ row_start){
  int i = blockIdx.x*blockDim.x + threadIdx.x;
  if(i > NPTS) return;
  int E = *erealp;
  int lo=0, hi=E;
  while(lo<hi){ int mid=(lo+hi)>>1; if(src[mid] < i) lo=mid+1; else hi=mid; }
  row_start[i] = lo;
}

__global__ void k_build_f(const float* __restrict__ feats, float* __restrict__ f){
  int idx = blockIdx.x*blockDim.x + threadIdx.x;
  if(idx >= NPTS*13) return;
  int i = idx/13, c = idx - i*13;
  f[idx] = (c==0) ? 1.f : feats[i*12 + (c-1)];
}

// ---- feature pre-pass: relu + split + pack, once per layer.
__global__ void k_cvtF(const float* __restrict__ x, unsigned* __restrict__ Fp, int total){
  int idx = blockIdx.x*blockDim.x + threadIdx.x;
  if(idx >= total) return;
  Fp[idx] = packf(fmaxf(x[idx], 0.f));
}

// ---------------- per-edge geometry (exact port of ball_to_cube + window) ----------------
__device__ __forceinline__ void edge_geom(float ox, float oy, float oz,
                                          float& win, float& t0, float& t1, float& t2, int& f0p){
  const float eps = 1e-9f;
  float sq = ox*ox + oy*oy + oz*oz;
  float u = 1.f - sq;
  win = fminf(fmaxf(u*u*u, 0.f), 1.f);
  float norm = sqrtf(sq + eps);
  float rxy2 = ox*ox + oy*oy;
  bool polar = (1.25f*oz*oz > rxy2);
  float s_p = sqrtf(3.f*norm/(norm + fabsf(oz) + eps));
  float s_n = norm / sqrtf(rxy2 + eps);
  float s = polar ? s_p : s_n;
  float xc = ox*s, yc = oy*s;
  float zc = polar ? sgnf(oz)*norm : 1.5f*oz;
  if(sq < 1e-12f){ xc = 0.f; yc = 0.f; zc = 0.f; }
  float r = sqrtf(xc*xc + yc*yc + eps);
  bool c1 = fabsf(xc) >= fabsf(yc);
  float xs = (fabsf(xc) < eps) ? eps : xc;
  float ys = (fabsf(yc) < eps) ? eps : yc;
  const float fop = 1.2732395447351628f; // float32(4/pi)
  float a = c1 ? sgnf(xc)*r : sgnf(yc)*r*fop*atanf(xc/ys);
  float b = c1 ? sgnf(xc)*r*fop*atanf(yc/xs) : sgnf(yc)*r;
  if(xc*xc + yc*yc < 1e-12f){ a = 0.f; b = 0.f; }
  float g0 = fminf(fmaxf((a *0.5f+0.5f)*3.f, 0.f), 3.f);
  float g1 = fminf(fmaxf((b *0.5f+0.5f)*3.f, 0.f), 3.f);
  float g2 = fminf(fmaxf((zc*0.5f+0.5f)*3.f, 0.f), 3.f);
  float f00 = floorf(g0), f01 = floorf(g1), f02 = floorf(g2);
  t0 = g0 - f00; t1 = g1 - f01; t2 = g2 - f02;
  f0p = (int)f00 | ((int)f01 << 2) | ((int)f02 << 4);
}

// ---- k_geom: per-edge staged data, computed ONCE (shared by all 4 scatter layers).
__global__ __launch_bounds__(256) void k_geom(const float* __restrict__ pos,
    const int* __restrict__ esrc, const int* __restrict__ edst,
    float4* __restrict__ gw, int4* __restrict__ gmz)
{
  int e = blockIdx.x*blockDim.x + threadIdx.x;
  if(e >= EPAD) return;
  const int sn = esrc[e], d = edst[e];
  const float ox = (pos[d*3+0]-pos[sn*3+0])/RADF;
  const float oy = (pos[d*3+1]-pos[sn*3+1])/RADF;
  const float oz = (pos[d*3+2]-pos[sn*3+2])/RADF;
  float win, t0, t1, t2; int f0p;
  edge_geom(ox, oy, oz, win, t0, t1, t2, f0p);
  const int i0 = f0p & 3, i1 = (f0p>>2) & 3, i2 = f0p >> 4;
  const int X0 = i0 << 4, X1 = ((i0+1)&3) << 4;
  const int Y0 = i1 << 2, Y1 = ((i1+1)&3) << 2;
  const int Z0 = i2, Z1 = (i2+1) & 3;
  const float wx0 = win*(1.f-t0), wx1 = win*t0;
  const float wy0 = 1.f-t1, wy1 = t1;
  const float wz0 = 1.f-t2, wz1 = t2;
  gw[e] = make_float4(wx0*wy0, wx0*wy1, wx1*wy0, wx1*wy1);
  const int p0 = Z0 & 1;
  const float zA = p0 ? wz1 : wz0;                  // weight for parity-0 (even z) cell
  const int   cA = p0 ? Z1 : Z0;                    // even-z cell
  const int   cB = p0 ? Z0 : Z1;                    // odd-z cell
  const int cells0 = (X0|Y0|cA) | ((X0|Y1|cA)<<8) | ((X1|Y0|cA)<<16) | ((X1|Y1|cA)<<24);
  const int cells1 = (X0|Y0|cB) | ((X0|Y1|cB)<<8) | ((X1|Y0|cB)<<16) | ((X1|Y1|cB)<<24);
  gmz[e] = make_int4(__float_as_int(zA), cells0, cells1, d);
}

// ------- MFMA scatter CIN=64 (r12 structure), packed-B epilogue.
// OUT3=0 (layer 2): B row = 4160 u32 = 4096 conv cells + 64 appended packed self-features
// (dense-into-GEMM fusion: relu(x1)@d2w becomes K rows 4096..4159 of the GEMM).
template<int OUT3>
__global__ __launch_bounds__(256) void k_scat64m(
    const unsigned* __restrict__ Fp, const float4* __restrict__ gw,
    const int4* __restrict__ gmz, const int* __restrict__ row_start,
    unsigned* __restrict__ B, int node_base,
    const float* __restrict__ W3, float* __restrict__ out)
{
  __shared__ __align__(128) _Float16 Wh[64*32];
  __shared__ __align__(128) _Float16 Wl[64*32];
  __shared__ __align__(128) _Float16 Fh[64*32];
  __shared__ __align__(128) _Float16 Fl[64*32];
  __shared__ __align__(16) float4 Sq[32];
  __shared__ __align__(16) int4   Smd[32];
  __shared__ float red[16];

  const int tid  = threadIdx.x;
  const int node = node_base + blockIdx.x;
  const int wv   = tid >> 6;
  const int lane = tid & 63;
  const int frow = lane & 15;
  const int fb   = (lane >> 4) << 4;   // frag col byte offset

  floatx4 acc[4];
  #pragma unroll
  for(int nt=0;nt<4;++nt){ acc[nt][0]=0.f; acc[nt][1]=0.f; acc[nt][2]=0.f; acc[nt][3]=0.f; }

  half8_t hz;
  #pragma unroll
  for(int q8=0;q8<8;++q8) hz[q8] = (_Float16)0;

  const int e0 = row_start[node], e1 = row_start[node+1];

  for(int eb = e0; eb < e1; eb += 32){
    const int n = (e1 - eb < 32) ? (e1 - eb) : 32;
    __syncthreads();
    if(wv == 0){
      if(lane < 32){
        int ei = eb + lane; if(ei >= e1) ei = e1 - 1;
        Sq[lane]  = gw[ei];
        Smd[lane] = gmz[ei];
      }
    } else {
      for(int j = tid - 64; j < 512; j += 192){
        if(j < 256) ((half8_t*)Wh)[j]       = hz;
        else        ((half8_t*)Wl)[j - 256] = hz;
      }
    }
    __syncthreads();
    {
      half8_t hreg, lreg;
      #pragma unroll
      for(int j=0;j<8;++j){
        const int dst = Smd[wv*8 + j].w;
        const unsigned u = Fp[(size_t)dst*64 + lane];
        hreg[j] = lo16(u);
        lreg[j] = hi16(u);
      }
      *(half8_t*)swzp(Fh, (lane<<6) + (wv<<4)) = hreg;
      *(half8_t*)swzp(Fl, (lane<<6) + (wv<<4)) = lreg;
    }
    if(lane < 8){
      const int ei = wv*8 + lane;
      if(ei < n){
        const float4 q  = Sq[ei];
        const int4   md = Smd[ei];
        const float zA = __int_as_float(md.x), zB = 1.f - zA;
        #pragma unroll
        for(int t=0;t<8;++t){
          const int   cells = (t < 4) ? md.y : md.z;
          const float zz    = (t < 4) ? zA : zB;
          const int   cell  = (cells >> ((t & 3) * 8)) & 255;
          const float qq    = ((t&3)==0) ? q.x : ((t&3)==1) ? q.y : ((t&3)==2) ? q.z : q.w;
          const float wgt   = qq * zz;
          const _Float16 h  = (_Float16)wgt;
          *(_Float16*)swzp(Wh, (cell<<6) + (ei<<1)) = h;
          *(_Float16*)swzp(Wl, (cell<<6) + (ei<<1)) = (_Float16)(wgt - (float)h);
        }
      }
    }
    __syncthreads();
    const half8_t ah = *(const half8_t*)swzp(Wh, ((wv*16 + frow)<<6) + fb);
    const half8_t al = *(const half8_t*)swzp(Wl, ((wv*16 + frow)<<6) + fb);
    #pragma unroll
    for(int nt=0; nt<4; ++nt){
      const half8_t bh = *(const half8_t*)swzp(Fh, ((nt*16 + frow)<<6) + fb);
      const half8_t bl = *(const half8_t*)swzp(Fl, ((nt*16 + frow)<<6) + fb);
      acc[nt] = __builtin_amdgcn_mfma_f32_16x16x32_f16(ah, bh, acc[nt], 0, 0, 0);
      acc[nt] = __builtin_amdgcn_mfma_f32_16x16x32_f16(al, bh, acc[nt], 0, 0, 0);
      acc[nt] = __builtin_amdgcn_mfma_f32_16x16x32_f16(ah, bl, acc[nt], 0, 0, 0);
    }
  }

  if(!OUT3){
    unsigned* Bg = B + (size_t)blockIdx.x*4160;
    #pragma unroll
    for(int nt=0;nt<4;++nt)
      #pragma unroll
      for(int r=0;r<4;++r){
        const int cell = wv*16 + (lane>>4)*4 + r;
        Bg[cell*64 + nt*16 + (lane&15)] = packf(acc[nt][r]);
      }
    // appended dense rows: node's own packed features (already relu+split)
    if(tid < 64) Bg[4096 + tid] = Fp[(size_t)node*64 + tid];
  } else {
    float s0=0.f, s1=0.f, s2=0.f;
    #pragma unroll
    for(int nt=0;nt<4;++nt){
      #pragma unroll
      for(int r=0;r<4;++r){
        const int cell = wv*16 + (lane>>4)*4 + r;
        const int j3   = (cell*64 + nt*16 + (lane&15)) * 3;
        const float v  = acc[nt][r];
        s0 = fmaf(v, W3[j3+0], s0);
        s1 = fmaf(v, W3[j3+1], s1);
        s2 = fmaf(v, W3[j3+2], s2);
      }
    }
    #pragma unroll
    for(int off = 32; off > 0; off >>= 1){
      s0 += __shfl_down(s0, off);
      s1 += __shfl_down(s1, off);
      s2 += __shfl_down(s2, off);
    }
    if(lane == 0){
      red[wv*4+0] = s0; red[wv*4+1] = s1; red[wv*4+2] = s2;
    }
    __syncthreads();
    if(tid == 0 && node < NREAL){
      out[node*3+0] += (red[0]+red[4]+red[8] +red[12])*(1.f/128.f);
      out[node*3+1] += (red[1]+red[5]+red[9] +red[13])*(1.f/128.f);
      out[node*3+2] += (red[2]+red[6]+red[10]+red[14])*(1.f/128.f);
    }
  }
}

// ------- MFMA scatter CIN=96 (r12 structure), packed-B epilogue.
// B row = 6240 u32 = 6144 conv cells + 96 appended packed self-features (dense fusion).
__global__ __launch_bounds__(256) void k_scat96m(
    const unsigned* __restrict__ Fp, const float4* __restrict__ gw,
    const int4* __restrict__ gmz, const int* __restrict__ row_start,
    unsigned* __restrict__ B, int node_base)
{
  __shared__ __align__(128) _Float16 Wh[64*32];
  __shared__ __align__(128) _Float16 Wl[64*32];
  __shared__ __align__(128) _Float16 Fh[96*32];
  __shared__ __align__(128) _Float16 Fl[96*32];
  __shared__ __align__(16) float4 Sq[32];
  __shared__ __align__(16) int4   Smd[32];

  const int tid  = threadIdx.x;
  const int node = node_base + blockIdx.x;
  const int wv   = tid >> 6;
  const int lane = tid & 63;
  const int frow = lane & 15;
  const int fb   = (lane >> 4) << 4;

  floatx4 acc[6];
  #pragma unroll
  for(int nt=0;nt<6;++nt){ acc[nt][0]=0.f; acc[nt][1]=0.f; acc[nt][2]=0.f; acc[nt][3]=0.f; }

  half8_t hz;
  #pragma unroll
  for(int q8=0;q8<8;++q8) hz[q8] = (_Float16)0;

  const int e0 = row_start[node], e1 = row_start[node+1];

  for(int eb = e0; eb < e1; eb += 32){
    const int n = (e1 - eb < 32) ? (e1 - eb) : 32;
    __syncthreads();
    if(wv == 0){
      if(lane < 32){
        int ei = eb + lane; if(ei >= e1) ei = e1 - 1;
        Sq[lane]  = gw[ei];
        Smd[lane] = gmz[ei];
      }
    } else {
      for(int j = tid - 64; j < 512; j += 192){
        if(j < 256) ((half8_t*)Wh)[j]       = hz;
        else        ((half8_t*)Wl)[j - 256] = hz;
      }
    }
    __syncthreads();
    {
      half8_t h0, l0, h1, l1;
      #pragma unroll
      for(int j=0;j<8;++j){
        const int dst = Smd[wv*8 + j].w;
        const unsigned u = Fp[(size_t)dst*96 + lane];
        h0[j] = lo16(u);
        l0[j] = hi16(u);
        if(lane < 32){
          const unsigned u2 = Fp[(size_t)dst*96 + 64 + lane];
          h1[j] = lo16(u2);
          l1[j] = hi16(u2);
        }
      }
      *(half8_t*)swzp(Fh, (lane<<6) + (wv<<4)) = h0;
      *(half8_t*)swzp(Fl, (lane<<6) + (wv<<4)) = l0;
      if(lane < 32){
        *(half8_t*)swzp(Fh, ((64+lane)<<6) + (wv<<4)) = h1;
        *(half8_t*)swzp(Fl, ((64+lane)<<6) + (wv<<4)) = l1;
      }
    }
    if(lane < 8){
      const int ei = wv*8 + lane;
      if(ei < n){
        const float4 q  = Sq[ei];
        const int4   md = Smd[ei];
        const float zA = __int_as_float(md.x), zB = 1.f - zA;
        #pragma unroll
        for(int t=0;t<8;++t){
          const int   cells = (t < 4) ? md.y : md.z;
          const float zz    = (t < 4) ? zA : zB;
          const int   cell  = (cells >> ((t & 3) * 8)) & 255;
          const float qq    = ((t&3)==0) ? q.x : ((t&3)==1) ? q.y : ((t&3)==2) ? q.z : q.w;
          const float wgt   = qq * zz;
          const _Float16 h  = (_Float16)wgt;
          *(_Float16*)swzp(Wh, (cell<<6) + (ei<<1)) = h;
          *(_Float16*)swzp(Wl, (cell<<6) + (ei<<1)) = (_Float16)(wgt - (float)h);
        }
      }
    }
    __syncthreads();
    const half8_t ah = *(const half8_t*)swzp(Wh, ((wv*16 + frow)<<6) + fb);
    const half8_t al = *(const half8_t*)swzp(Wl, ((wv*16 + frow)<<6) + fb);
    #pragma unroll
    for(int nt=0; nt<6; ++nt){
      const half8_t bh = *(const half8_t*)swzp(Fh, ((nt*16 + frow)<<6) + fb);
      const half8_t bl = *(const half8_t*)swzp(Fl, ((nt*16 + frow)<<6) + fb);
      acc[nt] = __builtin_amdgcn_mfma_f32_16x16x32_f16(ah, bh, acc[nt], 0, 0, 0);
      acc[nt] = __builtin_amdgcn_mfma_f32_16x16x32_f16(al, bh, acc[nt], 0, 0, 0);
      acc[nt] = __builtin_amdgcn_mfma_f32_16x16x32_f16(ah, bl, acc[nt], 0, 0, 0);
    }
  }

  unsigned* Bg = B + (size_t)blockIdx.x*6240;
  #pragma unroll
  for(int nt=0;nt<6;++nt)
    #pragma unroll
    for(int r=0;r<4;++r){
      const int cell = wv*16 + (lane>>4)*4 + r;
      Bg[cell*96 + nt*16 + (lane&15)] = packf(acc[nt][r]);
    }
  if(tid < 96) Bg[6144 + tid] = Fp[(size_t)node*96 + tid];
}

// ------- scatter CIN=13 (RMW form), packed-B epilogue -------------------------------------
__global__ __launch_bounds__(128) void k_scat13(
    const float* __restrict__ feat, const float4* __restrict__ gw,
    const int4* __restrict__ gmz, const int* __restrict__ row_start,
    unsigned* __restrict__ B, int node_base)
{
  constexpr int CIN = 13, BSZ = KK*CIN, ESW = 4, CSTRIDE = BSZ + 8;
  __shared__ __align__(16) float Bl[ESW*CSTRIDE];
  const int tid  = threadIdx.x;
  const int node = node_base + blockIdx.x;

  for(int j = tid; j < ESW*CSTRIDE; j += 128) Bl[j] = 0.f;

  const int e0 = row_start[node], e1 = row_start[node+1];
  const int wv   = tid >> 6;
  const int lane = tid & 63;
  const int slot = lane >> 4;
  const int c    = lane & 15;
  const bool act = (c < CIN);
  float* Bp = Bl + slot*CSTRIDE;
  __syncthreads();

  if(act){
    for(int e = e0 + slot; e < e1; e += ESW){
      const float4 q  = gw[e];
      const int4   md = gmz[e];
      const float zA = __int_as_float(md.x);
      const float z  = wv ? (1.f - zA) : zA;
      const int   cp = wv ? md.z : md.y;
      float v = feat[(size_t)md.w*CIN + c] * z;
      const int b0 = ( cp        & 255)*CIN + c;
      const int b1 = ((cp >> 8)  & 255)*CIN + c;
      const int b2 = ((cp >> 16) & 255)*CIN + c;
      const int b3 = (((unsigned)cp) >> 24)*CIN + c;
      float o0 = Bp[b0], o1 = Bp[b1], o2 = Bp[b2], o3 = Bp[b3];
      o0 = fmaf(q.x, v, o0); o1 = fmaf(q.y, v, o1);
      o2 = fmaf(q.z, v, o2); o3 = fmaf(q.w, v, o3);
      Bp[b0] = o0; Bp[b1] = o1; Bp[b2] = o2; Bp[b3] = o3;
    }
  }
  __syncthreads();

  unsigned* Bg = B + (size_t)blockIdx.x*BSZ;
  for(int j = tid*4; j < BSZ; j += 512){
    float4 a = *(const float4*)&Bl[j];
    #pragma unroll
    for(int k = 1; k < ESW; ++k){
      const float4 t = *(const float4*)&Bl[k*CSTRIDE + j];
      a.x += t.x; a.y += t.y; a.z += t.z; a.w += t.w;
    }
    uint4 o;
    o.x = packf(a.x); o.y = packf(a.y); o.z = packf(a.z); o.w = packf(a.w);
    *(uint4*)&Bg[j] = o;
  }
}

// ---- W pre-pass: transpose + split fp32 -> f16 hi/lo. WhT/WlT layout [64 cols][Ktot k];
// conv weights at k=0..Kcnv-1.
__global__ void k_cvtW(const float* __restrict__ W, _Float16* __restrict__ WhT,
                       _Float16* __restrict__ WlT, int Kcnv, int Ktot)
{
  int idx = blockIdx.x*blockDim.x + threadIdx.x;
  if(idx >= 64*Kcnv) return;
  int o = idx / Kcnv, k = idx - o*Kcnv;
  float w = W[(size_t)k*64 + o];
  _Float16 h = (_Float16)w;
  WhT[(size_t)o*Ktot + k] = h;
  WlT[(size_t)o*Ktot + k] = (_Float16)(w - (float)h);
}

// ---- dense-weight append: dW[cin][64] -> WhT/WlT rows k = koff..koff+Kcin-1 (fusion).
__global__ void k_cvtWd(const float* __restrict__ dW, _Float16* __restrict__ WhT,
                        _Float16* __restrict__ WlT, int Kcin, int Ktot, int koff)
{
  int idx = blockIdx.x*blockDim.x + threadIdx.x;
  if(idx >= 64*Kcin) return;
  int o = idx / Kcin, c = idx - o*Kcin;
  float w = dW[(size_t)c*64 + o];
  _Float16 h = (_Float16)w;
  WhT[(size_t)o*Ktot + koff + c] = h;
  WlT[(size_t)o*Ktot + koff + c] = (_Float16)(w - (float)h);
}

// ---- MFMA GEMM: M=64 tile, packed pre-split A. Kd = TOTAL K (conv cells + fused dense).
__global__ __launch_bounds__(256) void k_gemm_mfma(
    const unsigned* __restrict__ Ap, const _Float16* __restrict__ WhT,
    const _Float16* __restrict__ WlT, float* __restrict__ P,
    int M, int Kd, int node_base, int ksteps_per)
{
  __shared__ __align__(128) _Float16 Ah[64*32];
  __shared__ __align__(128) _Float16 Al[64*32];
  __shared__ __align__(128) _Float16 Bh[64*32];
  __shared__ __align__(128) _Float16 Blo[64*32];
  const int tid = threadIdx.x;
  const int mbase = blockIdx.x * 64;
  const int s = blockIdx.y;
  const int kt0 = s * ksteps_per * 32;
  const int kt1 = min(Kd, kt0 + ksteps_per*32);
  const int wv = tid >> 6, lane = tid & 63;
  const int row  = tid >> 2;          // staging row (A row / W col), 0..63
  const int useg = (tid & 3) * 8;     // u32 seg (8 u32 per thread) within 32-wide tile
  const int sb   = (tid & 3) << 4;    // staging byte col (16B per thread per buf)
  const int frow = lane & 15;
  const int fb   = (lane >> 4) << 4;  // frag byte col

  floatx4 acc[4];
  #pragma unroll
  for(int c=0;c<4;++c){ acc[c][0]=0.f; acc[c][1]=0.f; acc[c][2]=0.f; acc[c][3]=0.f; }

  const int grow = mbase + row;
  const unsigned* Arow = (grow < M) ? (Ap + (size_t)grow*Kd) : nullptr;
  const _Float16* WhRow = WhT + (size_t)row*Kd;
  const _Float16* WlRow = WlT + (size_t)row*Kd;

  for(int kt = kt0; kt < kt1; kt += 32){
    unsigned au[8];
    if(Arow){
      *(uint4*)&au[0] = *(const uint4*)(Arow + kt + useg);
      *(uint4*)&au[4] = *(const uint4*)(Arow + kt + useg + 4);
    } else {
      #pragma unroll
      for(int j=0;j<8;++j) au[j] = 0u;
    }
    half8_t hv, lv;
    #pragma unroll
    for(int j=0;j<8;++j){
      hv[j] = lo16(au[j]);
      lv[j] = hi16(au[j]);
    }
    half8_t wh = *(const half8_t*)(WhRow + kt + useg);
    half8_t wl = *(const half8_t*)(WlRow + kt + useg);
    __syncthreads();                        // previous iter's frag reads complete
    *(half8_t*)swzp(Ah,  (row<<6) + sb) = hv;
    *(half8_t*)swzp(Al,  (row<<6) + sb) = lv;
    *(half8_t*)swzp(Bh,  (row<<6) + sb) = wh;
    *(half8_t*)swzp(Blo, (row<<6) + sb) = wl;
    __syncthreads();                        // staged tile visible
    const half8_t ah = *(const half8_t*)swzp(Ah, ((wv*16 + frow)<<6) + fb);
    const half8_t al = *(const half8_t*)swzp(Al, ((wv*16 + frow)<<6) + fb);
    #pragma unroll
    for(int c=0;c<4;++c){
      const half8_t bh = *(const half8_t*)swzp(Bh,  ((c*16 + frow)<<6) + fb);
      const half8_t bl = *(const half8_t*)swzp(Blo, ((c*16 + frow)<<6) + fb);
      acc[c] = __builtin_amdgcn_mfma_f32_16x16x32_f16(ah, bh, acc[c], 0, 0, 0);
      acc[c] = __builtin_amdgcn_mfma_f32_16x16x32_f16(al, bh, acc[c], 0, 0, 0);
      acc[c] = __builtin_amdgcn_mfma_f32_16x16x32_f16(ah, bl, acc[c], 0, 0, 0);
    }
  }

  const int prow0 = mbase + wv*16 + (lane>>4)*4;
  const int pcol  = lane & 15;
  #pragma unroll
  for(int c=0;c<4;++c){
    #pragma unroll
    for(int r=0;r<4;++r){
      const int rr = prow0 + r;
      if(rr < M)
        P[((size_t)s*NPTS + node_base + rr)*64 + c*16 + pcol] = acc[c][r];
    }
  }
}

// ---- combine partials: x[node*ldout+colofs+o] += sum_s P[s][node][o]
template<int S>
__global__ void k_combine(const float* __restrict__ P, float* __restrict__ x,
                          int ldout, int colofs)
{
  int idx = blockIdx.x*blockDim.x + threadIdx.x;
  if(idx >= NPTS*16) return;
  int node = idx >> 4, c4 = (idx & 15) * 4;
  float4 s = *(const float4*)(P + (size_t)node*64 + c4);
  #pragma unroll
  for(int k=1;k<S;++k){
    float4 t = *(const float4*)(P + ((size_t)k*NPTS + node)*64 + c4);
    s.x+=t.x; s.y+=t.y; s.z+=t.z; s.w+=t.w;
  }
  float* xp = x + (size_t)node*ldout + colofs + c4;
  float4 o = *(float4*)xp;
  o.x+=s.x; o.y+=s.y; o.z+=s.z; o.w+=s.w;
  *(float4*)xp = o;
}

// ---------------- dense/bias paths ----------------
__global__ void k_dense0(const float* __restrict__ f, const float* __restrict__ dW,
                         const float* __restrict__ db, const float* __restrict__ cb0,
                         float* __restrict__ out)
{
  int idx = blockIdx.x*blockDim.x + threadIdx.x;
  if(idx >= NPTS*96) return;
  int i = idx/96, c = idx - i*96;
  if(c < 64){ out[idx] = cb0[c]; return; }
  int o = c - 64;
  float s = db[o];
  const float* row = f + (size_t)i*13;
  #pragma unroll
  for(int j=0;j<13;++j) s = fmaf(row[j], dW[j*32+o], s);
  out[idx] = s;
}

// bias init (dense matvec now fused into the GEMM K): x = db + cb (+ resid)
__global__ void k_bias(const float* __restrict__ db, const float* __restrict__ cb,
                       const float* __restrict__ resid, float* __restrict__ out)
{
  int idx = blockIdx.x*blockDim.x + threadIdx.x;
  if(idx >= NPTS*64) return;
  int o = idx & 63;
  float s = db[o] + cb[o];
  if(resid) s += resid[idx];
  out[idx] = s;
}

__global__ void k_dense3(const float* __restrict__ x2, const float* __restrict__ dW,
                         const float* __restrict__ db, const float* __restrict__ cb,
                         float* __restrict__ out)
{
  int idx = blockIdx.x*blockDim.x + threadIdx.x;
  if(idx >= NREAL*3) return;
  int i = idx/3, o = idx - i*3;
  float s = db[o] + cb[o];
  const float* row = x2 + (size_t)i*64;
  for(int c=0;c<64;++c) s = fmaf(fmaxf(row[c],0.f), dW[c*3+o], s);
  out[idx] = s * (1.f/128.f);
}

// ---------------- host ----------------
static inline size_t alup(size_t x){ return (x + 255) & ~(size_t)255; }

static inline int calc_rows(size_t bcap, int u32row, int want){
  size_t perrow = (size_t)u32row * 4;
  size_t r = (perrow > 0) ? bcap / perrow : 0;
  if(r >= (size_t)want) return want;
  r = (r / 128) * 128;
  if(r < 128) r = 128;
  return (int)r;
}

extern "C" void kernel_launch(void* const* d_in, const int* in_sizes, int n_in,
                              void* d_out, int out_size, void* d_ws, size_t ws_size,
                              hipStream_t stream)
{
  const float* pos   = (const float*)d_in[0];
  const float* feats = (const float*)d_in[1];
  const int*   esrc  = (const int*)d_in[2];
  const int*   edst  = (const int*)d_in[3];
  const float* c0w = (const float*)d_in[4];
  const float* c0b = (const float*)d_in[5];
  const float* d0w = (const float*)d_in[6];
  const float* d0b = (const float*)d_in[7];
  const float* c1w = (const float*)d_in[8];
  const float* c1b = (const float*)d_in[9];
  const float* d1w = (const float*)d_in[10];
  const float* d1b = (const float*)d_in[11];
  const float* c2w = (const float*)d_in[12];
  const float* c2b = (const float*)d_in[13];
  const float* d2w = (const float*)d_in[14];
  const float* d2b = (const float*)d_in[15];
  const float* c3w = (const float*)d_in[16];
  const float* c3b = (const float*)d_in[17];
  const float* d3w = (const float*)d_in[18];
  const float* d3b = (const float*)d_in[19];
  float* out = (float*)d_out;

  char* w = (char*)d_ws;
  size_t off = 0;
  float* f  = (float*)(w+off); off += alup((size_t)NPTS*13*4);
  float* x0 = (float*)(w+off); off += alup((size_t)NPTS*96*4);
  float* x1 = (float*)(w+off); off += alup((size_t)NPTS*64*4);
  float* x2 = (float*)(w+off); off += alup((size_t)NPTS*64*4);
  int* row_start = (int*)(w+off); off += alup((size_t)(NPTS+1)*4);
  int* ereal = (int*)(w+off);     off += alup(16);
  float4* gw = (float4*)(w+off);  off += alup((size_t)EPAD*16);     // per-edge xy weights
  int4*  gmz = (int4*)(w+off);    off += alup((size_t)EPAD*16);     // per-edge zA+cells+dst
  float* P  = (float*)(w+off); off += alup((size_t)8*NPTS*64*4);    // split-K partials
  _Float16* whT = (_Float16*)(w+off); off += alup((size_t)64*6400*2); // W hi (transposed, Ktot<=6240)
  _Float16* wlT = (_Float16*)(w+off); off += alup((size_t)64*6400*2); // W lo (transposed)
  unsigned* Fp0 = (unsigned*)(w+off); off += alup((size_t)NPTS*96*4); // packed pre-split feats (96ch)
  unsigned* Fp1 = (unsigned*)(w+off); off += alup((size_t)NPTS*64*4); // packed pre-split feats (64ch)
  unsigned* B = (unsigned*)(w+off);                                   // packed pre-split B
  size_t bcap = (ws_size > off) ? (ws_size - off) : 0;

  k_find_ereal<<<1,1,0,stream>>>(edst, ereal);
  k_csr<<<(NPTS+1+255)/256,256,0,stream>>>(esrc, ereal, row_start);
  k_build_f<<<(NPTS*13+255)/256,256,0,stream>>>(feats, f);
  k_geom<<<(EPAD+255)/256,256,0,stream>>>(pos, esrc, edst, gw, gmz);

  // ---- layer 0: x0[:,0:64] = cconv0(f)+c0b ; x0[:,64:96] = f@d0w+d0b  (chunk 8192)
  k_dense0<<<(NPTS*96+255)/256,256,0,stream>>>(f, d0w, d0b, c0b, x0);
  {
    k_cvtW<<<(64*832+255)/256,256,0,stream>>>(c0w, whT, wlT, 832, 832);
    int rows = calc_rows(bcap, 832, 8192);
    for(int base = 0; base < NPTS; base += rows){
      int m = (NPTS - base < rows) ? (NPTS - base) : rows;
      k_scat13<<<m,128,0,stream>>>(f, gw, gmz, row_start, B, base);
      k_gemm_mfma<<<dim3((m+63)/64, 8),256,0,stream>>>(B, whT, wlT, P, m, 832, base, 4);
    }
    k_combine<8><<<(NPTS*16+255)/256,256,0,stream>>>(P, x0, 96, 0);
  }

  // ---- layer 1: x1 = cconv1(relu(x0)) + relu(x0)@d1w + d1b + c1b
  //      dense fused into GEMM: Kd = 6144 + 96
  k_bias<<<(NPTS*64+255)/256,256,0,stream>>>(d1b, c1b, nullptr, x1);
  {
    k_cvtW<<<(64*6144+255)/256,256,0,stream>>>(c1w, whT, wlT, 6144, 6240);
    k_cvtWd<<<(64*96+255)/256,256,0,stream>>>(d1w, whT, wlT, 96, 6240, 6144);
    k_cvtF<<<(NPTS*96+255)/256,256,0,stream>>>(x0, Fp0, NPTS*96);
    int rows = calc_rows(bcap, 6240, 4096);
    for(int base = 0; base < NPTS; base += rows){
      int m = (NPTS - base < rows) ? (NPTS - base) : rows;
      k_scat96m<<<m,256,0,stream>>>(Fp0, gw, gmz, row_start, B, base);
      k_gemm_mfma<<<dim3((m+63)/64, 8),256,0,stream>>>(B, whT, wlT, P, m, 6240, base, 25);
    }
    k_combine<8><<<(NPTS*16+255)/256,256,0,stream>>>(P, x1, 64, 0);
  }

  // ---- layer 2: x2 = cconv2(relu(x1)) + relu(x1)@d2w + d2b + c2b + x1
  //      dense fused into GEMM: Kd = 4096 + 64
  k_bias<<<(NPTS*64+255)/256,256,0,stream>>>(d2b, c2b, x1, x2);
  {
    k_cvtW<<<(64*4096+255)/256,256,0,stream>>>(c2w, whT, wlT, 4096, 4160);
    k_cvtWd<<<(64*64+255)/256,256,0,stream>>>(d2w, whT, wlT, 64, 4160, 4096);
    k_cvtF<<<(NPTS*64+255)/256,256,0,stream>>>(x1, Fp1, NPTS*64);
    int rows = calc_rows(bcap, 4160, 4096);
    for(int base = 0; base < NPTS; base += rows){
      int m = (NPTS - base < rows) ? (NPTS - base) : rows;
      k_scat64m<0><<<m,256,0,stream>>>(Fp1, gw, gmz, row_start, B, base, nullptr, nullptr);
      k_gemm_mfma<<<dim3((m+63)/64, 8),256,0,stream>>>(B, whT, wlT, P, m, 4160, base, 17);
    }
    k_combine<8><<<(NPTS*16+255)/256,256,0,stream>>>(P, x2, 64, 0);
  }

  // ---- layer 3 (fused): out = dense3 part, then scatter adds conv3 GEMV directly
  k_dense3<<<(NREAL*3+255)/256,256,0,stream>>>(x2, d3w, d3b, c3b, out);
  k_cvtF<<<(NPTS*64+255)/256,256,0,stream>>>(x2, Fp1, NPTS*64);
  k_scat64m<1><<<NPTS,256,0,stream>>>(Fp1, gw, gmz, row_start, nullptr, 0, c3w, out);
}

// Round 17
// 874.981 us; speedup vs baseline: 1.1798x; 1.0102x over previous
//
#include <hip/hip_runtime.h>
#include <math.h>

#define NPTS   20001
#define NREAL  20000
#define EPAD   1200000
#define KK     64
#define RADF   0.1125f

typedef _Float16 half8_t __attribute__((ext_vector_type(8)));
typedef float    floatx4 __attribute__((ext_vector_type(4)));

__device__ __forceinline__ float sgnf(float v){ return v>0.f ? 1.f : (v<0.f ? -1.f : 0.f); }
__device__ __forceinline__ _Float16 lo16(unsigned u){ return __builtin_bit_cast(_Float16, (unsigned short)(u & 0xffffu)); }
__device__ __forceinline__ _Float16 hi16(unsigned u){ return __builtin_bit_cast(_Float16, (unsigned short)(u >> 16)); }
// deterministic fp32 -> packed f16 hi/lo split (hi in low 16 bits).
__device__ __forceinline__ unsigned packf(float v){
  _Float16 h = (_Float16)v;
  _Float16 l = (_Float16)(v - (float)h);
  return (unsigned)__builtin_bit_cast(unsigned short, h)
       | ((unsigned)__builtin_bit_cast(unsigned short, l) << 16);
}

// byte-offset XOR swizzle for [rows][32]-half (64B-row) LDS tiles.
__device__ __forceinline__ void* swzp(void* base, int byteoff){
  return (void*)((char*)base + (byteoff ^ (((byteoff >> 6) & 7) << 4)));
}
__device__ __forceinline__ const void* swzp(const void* base, int byteoff){
  return (const void*)((const char*)base + (byteoff ^ (((byteoff >> 6) & 7) << 4)));
}

// ---------------- CSR build (edge_src is sorted; pad edges have dst==NREAL) ----------------
__global__ void k_find_ereal(const int* __restrict__ dst, int* __restrict__ ereal){
  int lo=0, hi=EPAD;
  while(lo<hi){ int mid=(lo+hi)>>1; if(dst[mid]==NREAL) hi=mid; else lo=mid+1; }
  *ereal = lo;
}

__global__ void k_csr(const int* __restrict__ src, const int* __restrict__ erealp,
                      int* __restrict__ row_start){
  int i = blockIdx.x*blockDim.x + threadIdx.x;
  if(i > NPTS) return;
  int E = *erealp;
  int lo=0, hi=E;
  while(lo<hi){ int mid=(lo+hi)>>1; if(src[mid] < i) lo=mid+1; else hi=mid; }
  row_start[i] = lo;
}

__global__ void k_build_f(const float* __restrict__ feats, float* __restrict__ f){
  int idx = blockIdx.x*blockDim.x + threadIdx.x;
  if(idx >= NPTS*13) return;
  int i = idx/13, c = idx - i*13;
  f[idx] = (c==0) ? 1.f : feats[i*12 + (c-1)];
}

// ---- feature pre-pass: relu + split + pack, once per layer.
__global__ void k_cvtF(const float* __restrict__ x, unsigned* __restrict__ Fp, int total){
  int idx = blockIdx.x*blockDim.x + threadIdx.x;
  if(idx >= total) return;
  Fp[idx] = packf(fmaxf(x[idx], 0.f));
}

// ---------------- per-edge geometry (exact port of ball_to_cube + window) ----------------
__device__ __forceinline__ void edge_geom(float ox, float oy, float oz,
                                          float& win, float& t0, float& t1, float& t2, int& f0p){
  const float eps = 1e-9f;
  float sq = ox*ox + oy*oy + oz*oz;
  float u = 1.f - sq;
  win = fminf(fmaxf(u*u*u, 0.f), 1.f);
  float norm = sqrtf(sq + eps);
  float rxy2 = ox*ox + oy*oy;
  bool polar = (1.25f*oz*oz > rxy2);
  float s_p = sqrtf(3.f*norm/(norm + fabsf(oz) + eps));
  float s_n = norm / sqrtf(rxy2 + eps);
  float s = polar ? s_p : s_n;
  float xc = ox*s, yc = oy*s;
  float zc = polar ? sgnf(oz)*norm : 1.5f*oz;
  if(sq < 1e-12f){ xc = 0.f; yc = 0.f; zc = 0.f; }
  float r = sqrtf(xc*xc + yc*yc + eps);
  bool c1 = fabsf(xc) >= fabsf(yc);
  float xs = (fabsf(xc) < eps) ? eps : xc;
  float ys = (fabsf(yc) < eps) ? eps : yc;
  const float fop = 1.2732395447351628f; // float32(4/pi)
  float a = c1 ? sgnf(xc)*r : sgnf(yc)*r*fop*atanf(xc/ys);
  float b = c1 ? sgnf(xc)*r*fop*atanf(yc/xs) : sgnf(yc)*r;
  if(xc*xc + yc*yc < 1e-12f){ a = 0.f; b = 0.f; }
  float g0 = fminf(fmaxf((a *0.5f+0.5f)*3.f, 0.f), 3.f);
  float g1 = fminf(fmaxf((b *0.5f+0.5f)*3.f, 0.f), 3.f);
  float g2 = fminf(fmaxf((zc*0.5f+0.5f)*3.f, 0.f), 3.f);
  float f00 = floorf(g0), f01 = floorf(g1), f02 = floorf(g2);
  t0 = g0 - f00; t1 = g1 - f01; t2 = g2 - f02;
  f0p = (int)f00 | ((int)f01 << 2) | ((int)f02 << 4);
}

// ---- k_geom: per-edge staged data, computed ONCE (shared by all 4 scatter layers).
__global__ __launch_bounds__(256) void k_geom(const float* __restrict__ pos,
    const int* __restrict__ esrc, const int* __restrict__ edst,
    float4* __restrict__ gw, int4* __restrict__ gmz)
{
  int e = blockIdx.x*blockDim.x + threadIdx.x;
  if(e >= EPAD) return;
  const int sn = esrc[e], d = edst[e];
  const float ox = (pos[d*3+0]-pos[sn*3+0])/RADF;
  const float oy = (pos[d*3+1]-pos[sn*3+1])/RADF;
  const float oz = (pos[d*3+2]-pos[sn*3+2])/RADF;
  float win, t0, t1, t2; int f0p;
  edge_geom(ox, oy, oz, win, t0, t1, t2, f0p);
  const int i0 = f0p & 3, i1 = (f0p>>2) & 3, i2 = f0p >> 4;
  const int X0 = i0 << 4, X1 = ((i0+1)&3) << 4;
  const int Y0 = i1 << 2, Y1 = ((i1+1)&3) << 2;
  const int Z0 = i2, Z1 = (i2+1) & 3;
  const float wx0 = win*(1.f-t0), wx1 = win*t0;
  const float wy0 = 1.f-t1, wy1 = t1;
  const float wz0 = 1.f-t2, wz1 = t2;
  gw[e] = make_float4(wx0*wy0, wx0*wy1, wx1*wy0, wx1*wy1);
  const int p0 = Z0 & 1;
  const float zA = p0 ? wz1 : wz0;                  // weight for parity-0 (even z) cell
  const int   cA = p0 ? Z1 : Z0;                    // even-z cell
  const int   cB = p0 ? Z0 : Z1;                    // odd-z cell
  const int cells0 = (X0|Y0|cA) | ((X0|Y1|cA)<<8) | ((X1|Y0|cA)<<16) | ((X1|Y1|cA)<<24);
  const int cells1 = (X0|Y0|cB) | ((X0|Y1|cB)<<8) | ((X1|Y0|cB)<<16) | ((X1|Y1|cB)<<24);
  gmz[e] = make_int4(__float_as_int(zA), cells0, cells1, d);
}

// ------- MFMA scatter CIN=64 (v7): 64-EDGE PHASES via dual 32-tiles.
// r8-r15 counters frozen (VALU 47%, Mfma 9%, Occ 39%) -> barrier-phase latency floor:
// 3 barriers per 32 edges, deg~57 -> 2 phases/node. v7 stages TWO K=32 tile pairs per
// phase (same proven [64x32] swizzled layout), 3 barriers per 64 edges, 2 MFMA rounds.
// Most nodes now do ONE phase. Tail tile stays zeroed -> round-2 adds 0 (bit-identical;
// accumulation order unchanged: edges 0-31 then 32-63). LDS ~34.9KB -> 4 blk/CU = 16
// waves >= measured 12.6 effective.
template<int OUT3>
__global__ __launch_bounds__(256) void k_scat64m(
    const unsigned* __restrict__ Fp, const float4* __restrict__ gw,
    const int4* __restrict__ gmz, const int* __restrict__ row_start,
    unsigned* __restrict__ B, int node_base,
    const float* __restrict__ W3, float* __restrict__ out)
{
  __shared__ __align__(128) _Float16 Wh0[64*32];
  __shared__ __align__(128) _Float16 Wl0[64*32];
  __shared__ __align__(128) _Float16 Wh1[64*32];
  __shared__ __align__(128) _Float16 Wl1[64*32];
  __shared__ __align__(128) _Float16 Fh0[64*32];
  __shared__ __align__(128) _Float16 Fl0[64*32];
  __shared__ __align__(128) _Float16 Fh1[64*32];
  __shared__ __align__(128) _Float16 Fl1[64*32];
  __shared__ __align__(16) float4 Sq[64];
  __shared__ __align__(16) int4   Smd[64];
  __shared__ float red[16];

  const int tid  = threadIdx.x;
  const int node = node_base + blockIdx.x;
  const int wv   = tid >> 6;
  const int lane = tid & 63;
  const int frow = lane & 15;
  const int fb   = (lane >> 4) << 4;   // frag col byte offset

  floatx4 acc[4];
  #pragma unroll
  for(int nt=0;nt<4;++nt){ acc[nt][0]=0.f; acc[nt][1]=0.f; acc[nt][2]=0.f; acc[nt][3]=0.f; }

  half8_t hz;
  #pragma unroll
  for(int q8=0;q8<8;++q8) hz[q8] = (_Float16)0;

  const int e0 = row_start[node], e1 = row_start[node+1];

  for(int eb = e0; eb < e1; eb += 64){
    const int n = (e1 - eb < 64) ? (e1 - eb) : 64;
    __syncthreads();                       // prior frag + Sq/Smd reads complete
    // ---- phase A: wave0 stages 64 edge records (coalesced); waves 1-3 zero both Wt pairs
    if(wv == 0){
      int ei = eb + lane; if(ei >= e1) ei = e1 - 1;   // clamp tail (scatter guarded by n)
      Sq[lane]  = gw[ei];
      Smd[lane] = gmz[ei];
    } else {
      for(int j = tid - 64; j < 1024; j += 192){
        if(j < 256)       ((half8_t*)Wh0)[j]       = hz;
        else if(j < 512)  ((half8_t*)Wl0)[j - 256] = hz;
        else if(j < 768)  ((half8_t*)Wh1)[j - 512] = hz;
        else              ((half8_t*)Wl1)[j - 768] = hz;
      }
    }
    __syncthreads();                       // Sq/Smd + zeroed Wt visible
    // ---- phase B: Ft staging for both tiles + distributed weight scatter (64 edges)
    {
      half8_t h0r, l0r, h1r, l1r;
      #pragma unroll
      for(int j=0;j<8;++j){
        const int d0 = Smd[wv*8 + j].w;
        const unsigned u0 = Fp[(size_t)d0*64 + lane];
        h0r[j] = lo16(u0);
        l0r[j] = hi16(u0);
        const int d1 = Smd[32 + wv*8 + j].w;
        const unsigned u1 = Fp[(size_t)d1*64 + lane];
        h1r[j] = lo16(u1);
        l1r[j] = hi16(u1);
      }
      *(half8_t*)swzp(Fh0, (lane<<6) + (wv<<4)) = h0r;
      *(half8_t*)swzp(Fl0, (lane<<6) + (wv<<4)) = l0r;
      *(half8_t*)swzp(Fh1, (lane<<6) + (wv<<4)) = h1r;
      *(half8_t*)swzp(Fl1, (lane<<6) + (wv<<4)) = l1r;
    }
    if(lane < 16){
      const int ei = wv*16 + lane;         // 4 waves x 16 = 64 edges
      if(ei < n){
        const float4 q  = Sq[ei];
        const int4   md = Smd[ei];
        const float zA = __int_as_float(md.x), zB = 1.f - zA;
        _Float16* Whp = (ei < 32) ? Wh0 : Wh1;
        _Float16* Wlp = (ei < 32) ? Wl0 : Wl1;
        const int ep = ei & 31;
        #pragma unroll
        for(int t=0;t<8;++t){
          const int   cells = (t < 4) ? md.y : md.z;
          const float zz    = (t < 4) ? zA : zB;
          const int   cell  = (cells >> ((t & 3) * 8)) & 255;
          const float qq    = ((t&3)==0) ? q.x : ((t&3)==1) ? q.y : ((t&3)==2) ? q.z : q.w;
          const float wgt   = qq * zz;
          const _Float16 h  = (_Float16)wgt;
          *(_Float16*)swzp(Whp, (cell<<6) + (ep<<1)) = h;
          *(_Float16*)swzp(Wlp, (cell<<6) + (ep<<1)) = (_Float16)(wgt - (float)h);
        }
      }
    }
    __syncthreads();                       // both tiles staged
    // ---- MFMA round 0 (edges eb..eb+31)
    {
      const half8_t ah = *(const half8_t*)swzp(Wh0, ((wv*16 + frow)<<6) + fb);
      const half8_t al = *(const half8_t*)swzp(Wl0, ((wv*16 + frow)<<6) + fb);
      #pragma unroll
      for(int nt=0; nt<4; ++nt){
        const half8_t bh = *(const half8_t*)swzp(Fh0, ((nt*16 + frow)<<6) + fb);
        const half8_t bl = *(const half8_t*)swzp(Fl0, ((nt*16 + frow)<<6) + fb);
        acc[nt] = __builtin_amdgcn_mfma_f32_16x16x32_f16(ah, bh, acc[nt], 0, 0, 0);
        acc[nt] = __builtin_amdgcn_mfma_f32_16x16x32_f16(al, bh, acc[nt], 0, 0, 0);
        acc[nt] = __builtin_amdgcn_mfma_f32_16x16x32_f16(ah, bl, acc[nt], 0, 0, 0);
      }
    }
    // ---- MFMA round 1 (edges eb+32..eb+63; zero tile on tail -> adds 0)
    {
      const half8_t ah = *(const half8_t*)swzp(Wh1, ((wv*16 + frow)<<6) + fb);
      const half8_t al = *(const half8_t*)swzp(Wl1, ((wv*16 + frow)<<6) + fb);
      #pragma unroll
      for(int nt=0; nt<4; ++nt){
        const half8_t bh = *(const half8_t*)swzp(Fh1, ((nt*16 + frow)<<6) + fb);
        const half8_t bl = *(const half8_t*)swzp(Fl1, ((nt*16 + frow)<<6) + fb);
        acc[nt] = __builtin_amdgcn_mfma_f32_16x16x32_f16(ah, bh, acc[nt], 0, 0, 0);
        acc[nt] = __builtin_amdgcn_mfma_f32_16x16x32_f16(al, bh, acc[nt], 0, 0, 0);
        acc[nt] = __builtin_amdgcn_mfma_f32_16x16x32_f16(ah, bl, acc[nt], 0, 0, 0);
      }
    }
  }

  if(!OUT3){
    unsigned* Bg = B + (size_t)blockIdx.x*4160;
    #pragma unroll
    for(int nt=0;nt<4;++nt)
      #pragma unroll
      for(int r=0;r<4;++r){
        const int cell = wv*16 + (lane>>4)*4 + r;
        Bg[cell*64 + nt*16 + (lane&15)] = packf(acc[nt][r]);
      }
    // appended dense rows: node's own packed features (already relu+split)
    if(tid < 64) Bg[4096 + tid] = Fp[(size_t)node*64 + tid];
  } else {
    float s0=0.f, s1=0.f, s2=0.f;
    #pragma unroll
    for(int nt=0;nt<4;++nt){
      #pragma unroll
      for(int r=0;r<4;++r){
        const int cell = wv*16 + (lane>>4)*4 + r;
        const int j3   = (cell*64 + nt*16 + (lane&15)) * 3;
        const float v  = acc[nt][r];
        s0 = fmaf(v, W3[j3+0], s0);
        s1 = fmaf(v, W3[j3+1], s1);
        s2 = fmaf(v, W3[j3+2], s2);
      }
    }
    #pragma unroll
    for(int off = 32; off > 0; off >>= 1){
      s0 += __shfl_down(s0, off);
      s1 += __shfl_down(s1, off);
      s2 += __shfl_down(s2, off);
    }
    if(lane == 0){
      red[wv*4+0] = s0; red[wv*4+1] = s1; red[wv*4+2] = s2;
    }
    __syncthreads();
    if(tid == 0 && node < NREAL){
      out[node*3+0] += (red[0]+red[4]+red[8] +red[12])*(1.f/128.f);
      out[node*3+1] += (red[1]+red[5]+red[9] +red[13])*(1.f/128.f);
      out[node*3+2] += (red[2]+red[6]+red[10]+red[14])*(1.f/128.f);
    }
  }
}

// ------- MFMA scatter CIN=96 (r12 structure), packed-B epilogue.
// B row = 6240 u32 = 6144 conv cells + 96 appended packed self-features (dense fusion).
__global__ __launch_bounds__(256) void k_scat96m(
    const unsigned* __restrict__ Fp, const float4* __restrict__ gw,
    const int4* __restrict__ gmz, const int* __restrict__ row_start,
    unsigned* __restrict__ B, int node_base)
{
  __shared__ __align__(128) _Float16 Wh[64*32];
  __shared__ __align__(128) _Float16 Wl[64*32];
  __shared__ __align__(128) _Float16 Fh[96*32];
  __shared__ __align__(128) _Float16 Fl[96*32];
  __shared__ __align__(16) float4 Sq[32];
  __shared__ __align__(16) int4   Smd[32];

  const int tid  = threadIdx.x;
  const int node = node_base + blockIdx.x;
  const int wv   = tid >> 6;
  const int lane = tid & 63;
  const int frow = lane & 15;
  const int fb   = (lane >> 4) << 4;

  floatx4 acc[6];
  #pragma unroll
  for(int nt=0;nt<6;++nt){ acc[nt][0]=0.f; acc[nt][1]=0.f; acc[nt][2]=0.f; acc[nt][3]=0.f; }

  half8_t hz;
  #pragma unroll
  for(int q8=0;q8<8;++q8) hz[q8] = (_Float16)0;

  const int e0 = row_start[node], e1 = row_start[node+1];

  for(int eb = e0; eb < e1; eb += 32){
    const int n = (e1 - eb < 32) ? (e1 - eb) : 32;
    __syncthreads();
    if(wv == 0){
      if(lane < 32){
        int ei = eb + lane; if(ei >= e1) ei = e1 - 1;
        Sq[lane]  = gw[ei];
        Smd[lane] = gmz[ei];
      }
    } else {
      for(int j = tid - 64; j < 512; j += 192){
        if(j < 256) ((half8_t*)Wh)[j]       = hz;
        else        ((half8_t*)Wl)[j - 256] = hz;
      }
    }
    __syncthreads();
    {
      half8_t h0, l0, h1, l1;
      #pragma unroll
      for(int j=0;j<8;++j){
        const int dst = Smd[wv*8 + j].w;
        const unsigned u = Fp[(size_t)dst*96 + lane];
        h0[j] = lo16(u);
        l0[j] = hi16(u);
        if(lane < 32){
          const unsigned u2 = Fp[(size_t)dst*96 + 64 + lane];
          h1[j] = lo16(u2);
          l1[j] = hi16(u2);
        }
      }
      *(half8_t*)swzp(Fh, (lane<<6) + (wv<<4)) = h0;
      *(half8_t*)swzp(Fl, (lane<<6) + (wv<<4)) = l0;
      if(lane < 32){
        *(half8_t*)swzp(Fh, ((64+lane)<<6) + (wv<<4)) = h1;
        *(half8_t*)swzp(Fl, ((64+lane)<<6) + (wv<<4)) = l1;
      }
    }
    if(lane < 8){
      const int ei = wv*8 + lane;
      if(ei < n){
        const float4 q  = Sq[ei];
        const int4   md = Smd[ei];
        const float zA = __int_as_float(md.x), zB = 1.f - zA;
        #pragma unroll
        for(int t=0;t<8;++t){
          const int   cells = (t < 4) ? md.y : md.z;
          const float zz    = (t < 4) ? zA : zB;
          const int   cell  = (cells >> ((t & 3) * 8)) & 255;
          const float qq    = ((t&3)==0) ? q.x : ((t&3)==1) ? q.y : ((t&3)==2) ? q.z : q.w;
          const float wgt   = qq * zz;
          const _Float16 h  = (_Float16)wgt;
          *(_Float16*)swzp(Wh, (cell<<6) + (ei<<1)) = h;
          *(_Float16*)swzp(Wl, (cell<<6) + (ei<<1)) = (_Float16)(wgt - (float)h);
        }
      }
    }
    __syncthreads();
    const half8_t ah = *(const half8_t*)swzp(Wh, ((wv*16 + frow)<<6) + fb);
    const half8_t al = *(const half8_t*)swzp(Wl, ((wv*16 + frow)<<6) + fb);
    #pragma unroll
    for(int nt=0; nt<6; ++nt){
      const half8_t bh = *(const half8_t*)swzp(Fh, ((nt*16 + frow)<<6) + fb);
      const half8_t bl = *(const half8_t*)swzp(Fl, ((nt*16 + frow)<<6) + fb);
      acc[nt] = __builtin_amdgcn_mfma_f32_16x16x32_f16(ah, bh, acc[nt], 0, 0, 0);
      acc[nt] = __builtin_amdgcn_mfma_f32_16x16x32_f16(al, bh, acc[nt], 0, 0, 0);
      acc[nt] = __builtin_amdgcn_mfma_f32_16x16x32_f16(ah, bl, acc[nt], 0, 0, 0);
    }
  }

  unsigned* Bg = B + (size_t)blockIdx.x*6240;
  #pragma unroll
  for(int nt=0;nt<6;++nt)
    #pragma unroll
    for(int r=0;r<4;++r){
      const int cell = wv*16 + (lane>>4)*4 + r;
      Bg[cell*96 + nt*16 + (lane&15)] = packf(acc[nt][r]);
    }
  if(tid < 96) Bg[6144 + tid] = Fp[(size_t)node*96 + tid];
}

// ------- scatter CIN=13 (RMW form), packed-B epilogue -------------------------------------
__global__ __launch_bounds__(128) void k_scat13(
    const float* __restrict__ feat, const float4* __restrict__ gw,
    const int4* __restrict__ gmz, const int* __restrict__ row_start,
    unsigned* __restrict__ B, int node_base)
{
  constexpr int CIN = 13, BSZ = KK*CIN, ESW = 4, CSTRIDE = BSZ + 8;
  __shared__ __align__(16) float Bl[ESW*CSTRIDE];
  const int tid  = threadIdx.x;
  const int node = node_base + blockIdx.x;

  for(int j = tid; j < ESW*CSTRIDE; j += 128) Bl[j] = 0.f;

  const int e0 = row_start[node], e1 = row_start[node+1];
  const int wv   = tid >> 6;
  const int lane = tid & 63;
  const int slot = lane >> 4;
  const int c    = lane & 15;
  const bool act = (c < CIN);
  float* Bp = Bl + slot*CSTRIDE;
  __syncthreads();

  if(act){
    for(int e = e0 + slot; e < e1; e += ESW){
      const float4 q  = gw[e];
      const int4   md = gmz[e];
      const float zA = __int_as_float(md.x);
      const float z  = wv ? (1.f - zA) : zA;
      const int   cp = wv ? md.z : md.y;
      float v = feat[(size_t)md.w*CIN + c] * z;
      const int b0 = ( cp        & 255)*CIN + c;
      const int b1 = ((cp >> 8)  & 255)*CIN + c;
      const int b2 = ((cp >> 16) & 255)*CIN + c;
      const int b3 = (((unsigned)cp) >> 24)*CIN + c;
      float o0 = Bp[b0], o1 = Bp[b1], o2 = Bp[b2], o3 = Bp[b3];
      o0 = fmaf(q.x, v, o0); o1 = fmaf(q.y, v, o1);
      o2 = fmaf(q.z, v, o2); o3 = fmaf(q.w, v, o3);
      Bp[b0] = o0; Bp[b1] = o1; Bp[b2] = o2; Bp[b3] = o3;
    }
  }
  __syncthreads();

  unsigned* Bg = B + (size_t)blockIdx.x*BSZ;
  for(int j = tid*4; j < BSZ; j += 512){
    float4 a = *(const float4*)&Bl[j];
    #pragma unroll
    for(int k = 1; k < ESW; ++k){
      const float4 t = *(const float4*)&Bl[k*CSTRIDE + j];
      a.x += t.x; a.y += t.y; a.z += t.z; a.w += t.w;
    }
    uint4 o;
    o.x = packf(a.x); o.y = packf(a.y); o.z = packf(a.z); o.w = packf(a.w);
    *(uint4*)&Bg[j] = o;
  }
}

// ---- W pre-pass: transpose + split fp32 -> f16 hi/lo. WhT/WlT layout [64 cols][Ktot k];
// conv weights at k=0..Kcnv-1.
__global__ void k_cvtW(const float* __restrict__ W, _Float16* __restrict__ WhT,
                       _Float16* __restrict__ WlT, int Kcnv, int Ktot)
{
  int idx = blockIdx.x*blockDim.x + threadIdx.x;
  if(idx >= 64*Kcnv) return;
  int o = idx / Kcnv, k = idx - o*Kcnv;
  float w = W[(size_t)k*64 + o];
  _Float16 h = (_Float16)w;
  WhT[(size_t)o*Ktot + k] = h;
  WlT[(size_t)o*Ktot + k] = (_Float16)(w - (float)h);
}

// ---- dense-weight append: dW[cin][64] -> WhT/WlT rows k = koff..koff+Kcin-1 (fusion).
__global__ void k_cvtWd(const float* __restrict__ dW, _Float16* __restrict__ WhT,
                        _Float16* __restrict__ WlT, int Kcin, int Ktot, int koff)
{
  int idx = blockIdx.x*blockDim.x + threadIdx.x;
  if(idx >= 64*Kcin) return;
  int o = idx / Kcin, c = idx - o*Kcin;
  float w = dW[(size_t)c*64 + o];
  _Float16 h = (_Float16)w;
  WhT[(size_t)o*Ktot + koff + c] = h;
  WlT[(size_t)o*Ktot + koff + c] = (_Float16)(w - (float)h);
}

// ---- MFMA GEMM: M=64 tile, packed pre-split A. Kd = TOTAL K (conv cells + fused dense).
__global__ __launch_bounds__(256) void k_gemm_mfma(
    const unsigned* __restrict__ Ap, const _Float16* __restrict__ WhT,
    const _Float16* __restrict__ WlT, float* __restrict__ P,
    int M, int Kd, int node_base, int ksteps_per)
{
  __shared__ __align__(128) _Float16 Ah[64*32];
  __shared__ __align__(128) _Float16 Al[64*32];
  __shared__ __align__(128) _Float16 Bh[64*32];
  __shared__ __align__(128) _Float16 Blo[64*32];
  const int tid = threadIdx.x;
  const int mbase = blockIdx.x * 64;
  const int s = blockIdx.y;
  const int kt0 = s * ksteps_per * 32;
  const int kt1 = min(Kd, kt0 + ksteps_per*32);
  const int wv = tid >> 6, lane = tid & 63;
  const int row  = tid >> 2;          // staging row (A row / W col), 0..63
  const int useg = (tid & 3) * 8;     // u32 seg (8 u32 per thread) within 32-wide tile
  const int sb   = (tid & 3) << 4;    // staging byte col (16B per thread per buf)
  const int frow = lane & 15;
  const int fb   = (lane >> 4) << 4;  // frag byte col

  floatx4 acc[4];
  #pragma unroll
  for(int c=0;c<4;++c){ acc[c][0]=0.f; acc[c][1]=0.f; acc[c][2]=0.f; acc[c][3]=0.f; }

  const int grow = mbase + row;
  const unsigned* Arow = (grow < M) ? (Ap + (size_t)grow*Kd) : nullptr;
  const _Float16* WhRow = WhT + (size_t)row*Kd;
  const _Float16* WlRow = WlT + (size_t)row*Kd;

  for(int kt = kt0; kt < kt1; kt += 32){
    unsigned au[8];
    if(Arow){
      *(uint4*)&au[0] = *(const uint4*)(Arow + kt + useg);
      *(uint4*)&au[4] = *(const uint4*)(Arow + kt + useg + 4);
    } else {
      #pragma unroll
      for(int j=0;j<8;++j) au[j] = 0u;
    }
    half8_t hv, lv;
    #pragma unroll
    for(int j=0;j<8;++j){
      hv[j] = lo16(au[j]);
      lv[j] = hi16(au[j]);
    }
    half8_t wh = *(const half8_t*)(WhRow + kt + useg);
    half8_t wl = *(const half8_t*)(WlRow + kt + useg);
    __syncthreads();                        // previous iter's frag reads complete
    *(half8_t*)swzp(Ah,  (row<<6) + sb) = hv;
    *(half8_t*)swzp(Al,  (row<<6) + sb) = lv;
    *(half8_t*)swzp(Bh,  (row<<6) + sb) = wh;
    *(half8_t*)swzp(Blo, (row<<6) + sb) = wl;
    __syncthreads();                        // staged tile visible
    const half8_t ah = *(const half8_t*)swzp(Ah, ((wv*16 + frow)<<6) + fb);
    const half8_t al = *(const half8_t*)swzp(Al, ((wv*16 + frow)<<6) + fb);
    #pragma unroll
    for(int c=0;c<4;++c){
      const half8_t bh = *(const half8_t*)swzp(Bh,  ((c*16 + frow)<<6) + fb);
      const half8_t bl = *(const half8_t*)swzp(Blo, ((c*16 + frow)<<6) + fb);
      acc[c] = __builtin_amdgcn_mfma_f32_16x16x32_f16(ah, bh, acc[c], 0, 0, 0);
      acc[c] = __builtin_amdgcn_mfma_f32_16x16x32_f16(al, bh, acc[c], 0, 0, 0);
      acc[c] = __builtin_amdgcn_mfma_f32_16x16x32_f16(ah, bl, acc[c], 0, 0, 0);
    }
  }

  const int prow0 = mbase + wv*16 + (lane>>4)*4;
  const int pcol  = lane & 15;
  #pragma unroll
  for(int c=0;c<4;++c){
    #pragma unroll
    for(int r=0;r<4;++r){
      const int rr = prow0 + r;
      if(rr < M)
        P[((size_t)s*NPTS + node_base + rr)*64 + c*16 + pcol] = acc[c][r];
    }
  }
}

// ---- combine partials: x[node*ldout+colofs+o] += sum_s P[s][node][o]
template<int S>
__global__ void k_combine(const float* __restrict__ P, float* __restrict__ x,
                          int ldout, int colofs)
{
  int idx = blockIdx.x*blockDim.x + threadIdx.x;
  if(idx >= NPTS*16) return;
  int node = idx >> 4, c4 = (idx & 15) * 4;
  float4 s = *(const float4*)(P + (size_t)node*64 + c4);
  #pragma unroll
  for(int k=1;k<S;++k){
    float4 t = *(const float4*)(P + ((size_t)k*NPTS + node)*64 + c4);
    s.x+=t.x; s.y+=t.y; s.z+=t.z; s.w+=t.w;
  }
  float* xp = x + (size_t)node*ldout + colofs + c4;
  float4 o = *(float4*)xp;
  o.x+=s.x; o.y+=s.y; o.z+=s.z; o.w+=s.w;
  *(float4*)xp = o;
}

// ---------------- dense/bias paths ----------------
__global__ void k_dense0(const float* __restrict__ f, const float* __restrict__ dW,
                         const float* __restrict__ db, const float* __restrict__ cb0,
                         float* __restrict__ out)
{
  int idx = blockIdx.x*blockDim.x + threadIdx.x;
  if(idx >= NPTS*96) return;
  int i = idx/96, c = idx - i*96;
  if(c < 64){ out[idx] = cb0[c]; return; }
  int o = c - 64;
  float s = db[o];
  const float* row = f + (size_t)i*13;
  #pragma unroll
  for(int j=0;j<13;++j) s = fmaf(row[j], dW[j*32+o], s);
  out[idx] = s;
}

// bias init (dense matvec now fused into the GEMM K): x = db + cb (+ resid)
__global__ void k_bias(const float* __restrict__ db, const float* __restrict__ cb,
                       const float* __restrict__ resid, float* __restrict__ out)
{
  int idx = blockIdx.x*blockDim.x + threadIdx.x;
  if(idx >= NPTS*64) return;
  int o = idx & 63;
  float s = db[o] + cb[o];
  if(resid) s += resid[idx];
  out[idx] = s;
}

__global__ void k_dense3(const float* __restrict__ x2, const float* __restrict__ dW,
                         const float* __restrict__ db, const float* __restrict__ cb,
                         float* __restrict__ out)
{
  int idx = blockIdx.x*blockDim.x + threadIdx.x;
  if(idx >= NREAL*3) return;
  int i = idx/3, o = idx - i*3;
  float s = db[o] + cb[o];
  const float* row = x2 + (size_t)i*64;
  for(int c=0;c<64;++c) s = fmaf(fmaxf(row[c],0.f), dW[c*3+o], s);
  out[idx] = s * (1.f/128.f);
}

// ---------------- host ----------------
static inline size_t alup(size_t x){ return (x + 255) & ~(size_t)255; }

static inline int calc_rows(size_t bcap, int u32row, int want){
  size_t perrow = (size_t)u32row * 4;
  size_t r = (perrow > 0) ? bcap / perrow : 0;
  if(r >= (size_t)want) return want;
  r = (r / 128) * 128;
  if(r < 128) r = 128;
  return (int)r;
}

extern "C" void kernel_launch(void* const* d_in, const int* in_sizes, int n_in,
                              void* d_out, int out_size, void* d_ws, size_t ws_size,
                              hipStream_t stream)
{
  const float* pos   = (const float*)d_in[0];
  const float* feats = (const float*)d_in[1];
  const int*   esrc  = (const int*)d_in[2];
  const int*   edst  = (const int*)d_in[3];
  const float* c0w = (const float*)d_in[4];
  const float* c0b = (const float*)d_in[5];
  const float* d0w = (const float*)d_in[6];
  const float* d0b = (const float*)d_in[7];
  const float* c1w = (const float*)d_in[8];
  const float* c1b = (const float*)d_in[9];
  const float* d1w = (const float*)d_in[10];
  const float* d1b = (const float*)d_in[11];
  const float* c2w = (const float*)d_in[12];
  const float* c2b = (const float*)d_in[13];
  const float* d2w = (const float*)d_in[14];
  const float* d2b = (const float*)d_in[15];
  const float* c3w = (const float*)d_in[16];
  const float* c3b = (const float*)d_in[17];
  const float* d3w = (const float*)d_in[18];
  const float* d3b = (const float*)d_in[19];
  float* out = (float*)d_out;

  char* w = (char*)d_ws;
  size_t off = 0;
  float* f  = (float*)(w+off); off += alup((size_t)NPTS*13*4);
  float* x0 = (float*)(w+off); off += alup((size_t)NPTS*96*4);
  float* x1 = (float*)(w+off); off += alup((size_t)NPTS*64*4);
  float* x2 = (float*)(w+off); off += alup((size_t)NPTS*64*4);
  int* row_start = (int*)(w+off); off += alup((size_t)(NPTS+1)*4);
  int* ereal = (int*)(w+off);     off += alup(16);
  float4* gw = (float4*)(w+off);  off += alup((size_t)EPAD*16);     // per-edge xy weights
  int4*  gmz = (int4*)(w+off);    off += alup((size_t)EPAD*16);     // per-edge zA+cells+dst
  float* P  = (float*)(w+off); off += alup((size_t)8*NPTS*64*4);    // split-K partials
  _Float16* whT = (_Float16*)(w+off); off += alup((size_t)64*6400*2); // W hi (transposed, Ktot<=6240)
  _Float16* wlT = (_Float16*)(w+off); off += alup((size_t)64*6400*2); // W lo (transposed)
  unsigned* Fp0 = (unsigned*)(w+off); off += alup((size_t)NPTS*96*4); // packed pre-split feats (96ch)
  unsigned* Fp1 = (unsigned*)(w+off); off += alup((size_t)NPTS*64*4); // packed pre-split feats (64ch)
  unsigned* B = (unsigned*)(w+off);                                   // packed pre-split B
  size_t bcap = (ws_size > off) ? (ws_size - off) : 0;

  k_find_ereal<<<1,1,0,stream>>>(edst, ereal);
  k_csr<<<(NPTS+1+255)/256,256,0,stream>>>(esrc, ereal, row_start);
  k_build_f<<<(NPTS*13+255)/256,256,0,stream>>>(feats, f);
  k_geom<<<(EPAD+255)/256,256,0,stream>>>(pos, esrc, edst, gw, gmz);

  // ---- layer 0: x0[:,0:64] = cconv0(f)+c0b ; x0[:,64:96] = f@d0w+d0b  (chunk 8192)
  k_dense0<<<(NPTS*96+255)/256,256,0,stream>>>(f, d0w, d0b, c0b, x0);
  {
    k_cvtW<<<(64*832+255)/256,256,0,stream>>>(c0w, whT, wlT, 832, 832);
    int rows = calc_rows(bcap, 832, 8192);
    for(int base = 0; base < NPTS; base += rows){
      int m = (NPTS - base < rows) ? (NPTS - base) : rows;
      k_scat13<<<m,128,0,stream>>>(f, gw, gmz, row_start, B, base);
      k_gemm_mfma<<<dim3((m+63)/64, 8),256,0,stream>>>(B, whT, wlT, P, m, 832, base, 4);
    }
    k_combine<8><<<(NPTS*16+255)/256,256,0,stream>>>(P, x0, 96, 0);
  }

  // ---- layer 1: x1 = cconv1(relu(x0)) + relu(x0)@d1w + d1b + c1b
  //      dense fused into GEMM: Kd = 6144 + 96
  k_bias<<<(NPTS*64+255)/256,256,0,stream>>>(d1b, c1b, nullptr, x1);
  {
    k_cvtW<<<(64*6144+255)/256,256,0,stream>>>(c1w, whT, wlT, 6144, 6240);
    k_cvtWd<<<(64*96+255)/256,256,0,stream>>>(d1w, whT, wlT, 96, 6240, 6144);
    k_cvtF<<<(NPTS*96+255)/256,256,0,stream>>>(x0, Fp0, NPTS*96);
    int rows = calc_rows(bcap, 6240, 4096);
    for(int base = 0; base < NPTS; base += rows){
      int m = (NPTS - base < rows) ? (NPTS - base) : rows;
      k_scat96m<<<m,256,0,stream>>>(Fp0, gw, gmz, row_start, B, base);
      k_gemm_mfma<<<dim3((m+63)/64, 8),256,0,stream>>>(B, whT, wlT, P, m, 6240, base, 25);
    }
    k_combine<8><<<(NPTS*16+255)/256,256,0,stream>>>(P, x1, 64, 0);
  }

  // ---- layer 2: x2 = cconv2(relu(x1)) + relu(x1)@d2w + d2b + c2b + x1
  //      dense fused into GEMM: Kd = 4096 + 64
  k_bias<<<(NPTS*64+255)/256,256,0,stream>>>(d2b, c2b, x1, x2);
  {
    k_cvtW<<<(64*4096+255)/256,256,0,stream>>>(c2w, whT, wlT, 4096, 4160);
    k_cvtWd<<<(64*64+255)/256,256,0,stream>>>(d2w, whT, wlT, 64, 4160, 4096);
    k_cvtF<<<(NPTS*64+255)/256,256,0,stream>>>(x1, Fp1, NPTS*64);
    int rows = calc_rows(bcap, 4160, 4096);
    for(int base = 0; base < NPTS; base += rows){
      int m = (NPTS - base < rows) ? (NPTS - base) : rows;
      k_scat64m<0><<<m,256,0,stream>>>(Fp1, gw, gmz, row_start, B, base, nullptr, nullptr);
      k_gemm_mfma<<<dim3((m+63)/64, 8),256,0,stream>>>(B, whT, wlT, P, m, 4160, base, 17);
    }
    k_combine<8><<<(NPTS*16+255)/256,256,0,stream>>>(P, x2, 64, 0);
  }

  // ---- layer 3 (fused): out = dense3 part, then scatter adds conv3 GEMV directly
  k_dense3<<<(NREAL*3+255)/256,256,0,stream>>>(x2, d3w, d3b, c3b, out);
  k_cvtF<<<(NPTS*64+255)/256,256,0,stream>>>(x2, Fp1, NPTS*64);
  k_scat64m<1><<<NPTS,256,0,stream>>>(Fp1, gw, gmz, row_start, nullptr, 0, c3w, out);
}